// Round 1
// baseline (629.420 us; speedup 1.0000x reference)
//
#include <hip/hip_runtime.h>
#include <math.h>

#define DFEAT 256

// ---------------- graph setup ----------------
__global__ void k_deg(const int* __restrict__ dst, int E, int* __restrict__ deg) {
  int i = blockIdx.x * blockDim.x + threadIdx.x;
  if (i < E) atomicAdd(&deg[dst[i]], 1);
}

__global__ void k_invdeg(const int* __restrict__ deg, int N,
                         float* __restrict__ invd, float* __restrict__ mask) {
  int i = blockIdx.x * blockDim.x + threadIdx.x;
  if (i < N) {
    int d = deg[i];
    invd[i] = d > 0 ? 1.0f / (float)d : 0.0f;
    mask[i] = d > 0 ? 1.0f : 0.0f;
  }
}

// single-block exclusive scan: offs[0]=0, offs[i+1]=sum(deg[0..i])
__global__ void k_scan(const int* __restrict__ deg, int N, int* __restrict__ offs) {
  __shared__ int wsum[16];
  __shared__ int carry_s;
  const int tid = threadIdx.x, lane = tid & 63, wave = tid >> 6;
  if (tid == 0) { carry_s = 0; offs[0] = 0; }
  __syncthreads();
  for (int base = 0; base < N; base += 1024) {
    int i = base + tid;
    int v = (i < N) ? deg[i] : 0;
    int x = v;
    #pragma unroll
    for (int off = 1; off < 64; off <<= 1) {
      int t = __shfl_up(x, off);
      if (lane >= off) x += t;
    }
    if (lane == 63) wsum[wave] = x;
    __syncthreads();
    if (wave == 0 && lane < 16) {
      int w = wsum[lane];
      int y = w;
      #pragma unroll
      for (int off = 1; off < 16; off <<= 1) {
        int t = __shfl_up(y, off);
        if (lane >= off) y += t;
      }
      wsum[lane] = y - w;  // exclusive
    }
    __syncthreads();
    int incl = x + wsum[wave] + carry_s;
    if (i < N) offs[i + 1] = incl;
    __syncthreads();
    if (tid == 1023) carry_s = incl;
    __syncthreads();
  }
}

__global__ void k_fill(const int* __restrict__ src, const int* __restrict__ dst, int E,
                       int* __restrict__ cursor, int* __restrict__ csr) {
  int i = blockIdx.x * blockDim.x + threadIdx.x;
  if (i < E) {
    int p = atomicAdd(&cursor[dst[i]], 1);
    csr[p] = src[i];
  }
}

// ---------------- weight precompute ----------------
// sm[0..H-1] = softmax(gate), sm[32],sm[33] = softmax(hop_weights)
__global__ void k_softmax(const float* __restrict__ gate, int H,
                          const float* __restrict__ hopw, float* __restrict__ sm) {
  if (blockIdx.x == 0 && threadIdx.x == 0) {
    float mx = -1e30f;
    for (int h = 0; h < H; ++h) mx = fmaxf(mx, gate[h]);
    float s = 0.f;
    for (int h = 0; h < H; ++h) { float e = expf(gate[h] - mx); sm[h] = e; s += e; }
    for (int h = 0; h < H; ++h) sm[h] /= s;
    float m2 = fmaxf(hopw[0], hopw[1]);
    float e0 = expf(hopw[0] - m2), e1 = expf(hopw[1] - m2);
    sm[32] = e0 / (e0 + e1);
    sm[33] = e1 / (e0 + e1);
  }
}

__global__ void k_wbar(const float* __restrict__ Wh_w, const float* __restrict__ Wh_b, int H,
                       float* __restrict__ Wbar, float* __restrict__ bbar) {
  int j = blockIdx.x * 256 + threadIdx.x;  // 0..65535
  float s = 0.f;
  for (int h = 0; h < H; ++h) s += Wh_w[h * 65536 + j];
  Wbar[j] = s / (float)H;
  if (j < DFEAT) {
    float b = 0.f;
    for (int h = 0; h < H; ++h) b += Wh_b[h * DFEAT + j];
    bbar[j] = b / (float)H;
  }
}

// Wcat[i*256+d] = gates[i/32] * Wp_w flat (layouts coincide); bcat likewise
__global__ void k_wcat(const float* __restrict__ Wp_w, const float* __restrict__ Wp_b,
                       const float* __restrict__ sm, float* __restrict__ Wcat,
                       float* __restrict__ bcat) {
  int j = blockIdx.x * 256 + threadIdx.x;  // 0..65535
  Wcat[j] = sm[j >> 13] * Wp_w[j];         // j/(32*256) = head
  if (j < DFEAT) bcat[j] = sm[j >> 5] * Wp_b[j];
}

// C[i][d] = sum_k A[i][k]*B[k][d], all 256x256
__global__ void k_mm(const float* __restrict__ A, const float* __restrict__ B,
                     float* __restrict__ C) {
  int i = blockIdx.x, d = threadIdx.x;
  float c = 0.f;
  for (int k = 0; k < DFEAT; ++k) c = fmaf(A[i * DFEAT + k], B[k * DFEAT + d], c);
  C[i * DFEAT + d] = c;
}

__global__ void k_cvec(const float* __restrict__ Wcat, const float* __restrict__ W1,
                       const float* __restrict__ bbar, const float* __restrict__ sm,
                       float* __restrict__ c1s, float* __restrict__ c2s) {
  int i = threadIdx.x;  // 256
  float s1 = 0.f, s2 = 0.f;
  for (int k = 0; k < DFEAT; ++k) {
    float b = bbar[k];
    s1 = fmaf(Wcat[i * DFEAT + k], b, s1);
    s2 = fmaf(W1[i * DFEAT + k], b, s2);
  }
  float hw0 = sm[32], hw1 = sm[33];
  c1s[i] = (hw0 + hw1) * s1;
  c2s[i] = hw1 * s2;
}

// ---------------- edge pass: out[n] = inv_deg[n] * sum_{e: dst=n} x[src_e], one wave per node ----
template <bool DOF>
__global__ void k_agg(const float* __restrict__ x, const int* __restrict__ csr,
                      const int* __restrict__ offs, const float* __restrict__ invd,
                      int N, float* __restrict__ out,
                      const float* __restrict__ mask, float* __restrict__ f) {
  int wid = (blockIdx.x * blockDim.x + threadIdx.x) >> 6;
  int lane = threadIdx.x & 63;
  if (wid >= N) return;
  int beg = offs[wid], end = offs[wid + 1];
  float a0 = 0.f, a1 = 0.f, a2 = 0.f, a3 = 0.f, fm = 0.f;
  for (int e = beg; e < end; ++e) {
    int s = csr[e];
    const float4 v = *(reinterpret_cast<const float4*>(x + (size_t)s * DFEAT) + lane);
    a0 += v.x; a1 += v.y; a2 += v.z; a3 += v.w;
    if (DOF) fm += mask[s];
  }
  float w = invd[wid];
  float4 r = make_float4(a0 * w, a1 * w, a2 * w, a3 * w);
  *(reinterpret_cast<float4*>(out + (size_t)wid * DFEAT) + lane) = r;
  if (DOF && lane == 0) f[wid] = fm * w;
}

// ---------------- fused final GEMM (in place on d_out; blocks own full 256-wide rows) ----
__global__ __launch_bounds__(256) void k_final(
    float* __restrict__ out,        // N x 256, holds m0 on entry
    const float* __restrict__ mm0,  // N x 256
    const float* __restrict__ W1, const float* __restrict__ W2,
    const float* __restrict__ sm, const float* __restrict__ mask,
    const float* __restrict__ fbuf, const float* __restrict__ c1s,
    const float* __restrict__ c2s, const float* __restrict__ bcat, int N) {
  __shared__ float As[32][36];   // [row][kk], 144B row stride (16B aligned)
  __shared__ float Bs[32][260];  // [kk][col], 1040B row stride (16B aligned)
  const int tid = threadIdx.x;
  const int lane = tid & 63;
  const int wave = tid >> 6;
  const int r0 = blockIdx.x * 32;
  const int c0 = lane << 2;  // 4 consecutive output cols
  const int rt = wave << 3;  // 8 rows per thread
  const float hw0 = sm[32], hw1 = sm[33];

  float acc[8][4];
#pragma unroll
  for (int r = 0; r < 8; ++r)
#pragma unroll
    for (int j = 0; j < 4; ++j) acc[r][j] = 0.f;

  for (int k0 = 0; k0 < 2 * DFEAT; k0 += 32) {
    const float* Aptr = (k0 < DFEAT) ? out : mm0;
    const float* W = (k0 < DFEAT) ? W1 : W2;
    const float hw = (k0 < DFEAT) ? hw0 : hw1;
    const int kb = (k0 < DFEAT) ? k0 : (k0 - DFEAT);
    {  // A tile: 32 rows x 32 k, one float4 per thread
      const int row = tid >> 3;
      const int kc = (tid & 7) << 2;
      float4 v = make_float4(0.f, 0.f, 0.f, 0.f);
      const int gr = r0 + row;
      if (gr < N) v = *reinterpret_cast<const float4*>(Aptr + (size_t)gr * DFEAT + kb + kc);
      *reinterpret_cast<float4*>(&As[row][kc]) = v;
    }
    // B tile: Bs[kk][i] = hw * W[i][kb+kk]; coalesced float4 global reads
#pragma unroll
    for (int rep = 0; rep < 8; ++rep) {
      const int flat4 = rep * 256 + tid;  // 0..2047
      const int i = flat4 >> 3;
      const int kk0 = (flat4 & 7) << 2;
      const float4 v = *reinterpret_cast<const float4*>(W + i * DFEAT + kb + kk0);
      Bs[kk0 + 0][i] = hw * v.x;
      Bs[kk0 + 1][i] = hw * v.y;
      Bs[kk0 + 2][i] = hw * v.z;
      Bs[kk0 + 3][i] = hw * v.w;
    }
    __syncthreads();
#pragma unroll 2
    for (int k4 = 0; k4 < 32; k4 += 4) {
      float4 b4[4];
#pragma unroll
      for (int kk = 0; kk < 4; ++kk)
        b4[kk] = *reinterpret_cast<const float4*>(&Bs[k4 + kk][c0]);
#pragma unroll
      for (int r = 0; r < 8; ++r) {
        const float4 a4 = *reinterpret_cast<const float4*>(&As[rt + r][k4]);
        const float av[4] = {a4.x, a4.y, a4.z, a4.w};
#pragma unroll
        for (int kk = 0; kk < 4; ++kk) {
          acc[r][0] = fmaf(av[kk], b4[kk].x, acc[r][0]);
          acc[r][1] = fmaf(av[kk], b4[kk].y, acc[r][1]);
          acc[r][2] = fmaf(av[kk], b4[kk].z, acc[r][2]);
          acc[r][3] = fmaf(av[kk], b4[kk].w, acc[r][3]);
        }
      }
    }
    __syncthreads();
  }
  const float4 vc1 = *reinterpret_cast<const float4*>(c1s + c0);
  const float4 vc2 = *reinterpret_cast<const float4*>(c2s + c0);
  const float4 vb = *reinterpret_cast<const float4*>(bcat + c0);
#pragma unroll
  for (int r = 0; r < 8; ++r) {
    const int gr = r0 + rt + r;
    if (gr < N) {
      const float mk = mask[gr];
      const float fv = fbuf[gr];
      float4 o;
      o.x = acc[r][0] + mk * vc1.x + fv * vc2.x + vb.x;
      o.y = acc[r][1] + mk * vc1.y + fv * vc2.y + vb.y;
      o.z = acc[r][2] + mk * vc1.z + fv * vc2.z + vb.z;
      o.w = acc[r][3] + mk * vc1.w + fv * vc2.w + vb.w;
      *reinterpret_cast<float4*>(out + (size_t)gr * DFEAT + c0) = o;
    }
  }
}

// ---------------- host ----------------
extern "C" void kernel_launch(void* const* d_in, const int* in_sizes, int n_in,
                              void* d_out, int out_size, void* d_ws, size_t ws_size,
                              hipStream_t stream) {
  const float* x    = (const float*)d_in[0];
  const float* Wh_w = (const float*)d_in[1];
  const float* Wh_b = (const float*)d_in[2];
  const float* Wp_w = (const float*)d_in[3];
  const float* Wp_b = (const float*)d_in[4];
  const float* gate = (const float*)d_in[5];
  const float* hopw = (const float*)d_in[6];
  const int* src    = (const int*)d_in[7];
  const int* dst    = (const int*)d_in[8];

  const int H = in_sizes[5];          // 8
  const int E = in_sizes[7];          // 800000
  const int N = in_sizes[0] / DFEAT;  // 50000
  float* out = (float*)d_out;

  char* w = (char*)d_ws;
  auto take = [&](size_t bytes) -> char* {
    char* p = w;
    w += (bytes + 255) & ~(size_t)255;
    return p;
  };
  float* mm0   = (float*)take((size_t)N * DFEAT * 4);
  int* csr     = (int*)take((size_t)E * 4);
  int* offs    = (int*)take((size_t)(N + 1) * 4);
  int* cursor  = (int*)take((size_t)N * 4);
  int* deg     = (int*)take((size_t)N * 4);
  float* invd  = (float*)take((size_t)N * 4);
  float* mask  = (float*)take((size_t)N * 4);
  float* fbuf  = (float*)take((size_t)N * 4);
  float* Wbar  = (float*)take(65536 * 4);
  float* Wcat  = (float*)take(65536 * 4);
  float* W1    = (float*)take(65536 * 4);
  float* W2    = (float*)take(65536 * 4);
  float* bbar  = (float*)take(256 * 4);
  float* bcat  = (float*)take(256 * 4);
  float* c1s   = (float*)take(256 * 4);
  float* c2s   = (float*)take(256 * 4);
  float* sm    = (float*)take(64 * 4);

  // graph structure
  hipMemsetAsync(deg, 0, (size_t)N * 4, stream);
  k_deg<<<(E + 255) / 256, 256, 0, stream>>>(dst, E, deg);
  k_scan<<<1, 1024, 0, stream>>>(deg, N, offs);
  k_invdeg<<<(N + 255) / 256, 256, 0, stream>>>(deg, N, invd, mask);
  hipMemcpyAsync(cursor, offs, (size_t)N * 4, hipMemcpyDeviceToDevice, stream);
  k_fill<<<(E + 255) / 256, 256, 0, stream>>>(src, dst, E, cursor, csr);

  // folded weights
  k_softmax<<<1, 64, 0, stream>>>(gate, H, hopw, sm);
  k_wbar<<<256, 256, 0, stream>>>(Wh_w, Wh_b, H, Wbar, bbar);
  k_wcat<<<256, 256, 0, stream>>>(Wp_w, Wp_b, sm, Wcat, bcat);
  k_mm<<<256, 256, 0, stream>>>(Wcat, Wbar, W1);   // W1 = Wcat@Wbar
  k_mm<<<256, 256, 0, stream>>>(W1, Wbar, W2);     // W2 = W1@Wbar
  k_cvec<<<1, 256, 0, stream>>>(Wcat, W1, bbar, sm, c1s, c2s);

  // m0 = meanagg(x) -> d_out ; mm0 = meanagg(m0) (+ f = meanagg(mask))
  const int aggBlocks = (N + 3) / 4;  // 4 waves (nodes) per 256-thread block
  k_agg<false><<<aggBlocks, 256, 0, stream>>>(x, csr, offs, invd, N, out, nullptr, nullptr);
  k_agg<true><<<aggBlocks, 256, 0, stream>>>(out, csr, offs, invd, N, mm0, mask, fbuf);

  // out = hw0*m0@W1^T + hw1*mm0@W2^T + mask*c1s + f*c2s + bcat  (in place)
  k_final<<<(N + 31) / 32, 256, 0, stream>>>(out, mm0, W1, W2, sm, mask, fbuf,
                                             c1s, c2s, bcat, N);
}

// Round 2
// 597.051 us; speedup vs baseline: 1.0542x; 1.0542x over previous
//
#include <hip/hip_runtime.h>
#include <math.h>

#define DFEAT 256

// ---------------- graph setup ----------------
__global__ void k_deg(const int* __restrict__ dst, int E, int* __restrict__ deg) {
  int i = blockIdx.x * blockDim.x + threadIdx.x;
  if (i < E) atomicAdd(&deg[dst[i]], 1);
}

__global__ void k_invdeg(const int* __restrict__ deg, int N,
                         float* __restrict__ invd, float* __restrict__ mask) {
  int i = blockIdx.x * blockDim.x + threadIdx.x;
  if (i < N) {
    int d = deg[i];
    invd[i] = d > 0 ? 1.0f / (float)d : 0.0f;
    mask[i] = d > 0 ? 1.0f : 0.0f;
  }
}

// ---------------- parallel 3-phase exclusive scan ----------------
__device__ __forceinline__ int wave_incl_scan(int x, int lane) {
#pragma unroll
  for (int off = 1; off < 64; off <<= 1) {
    int t = __shfl_up(x, off);
    if (lane >= off) x += t;
  }
  return x;
}

__global__ void k_scan1(const int* __restrict__ deg, int N, int* __restrict__ bsum) {
  const int tid = threadIdx.x, lane = tid & 63, wave = tid >> 6;
  int i = blockIdx.x * 256 + tid;
  int v = (i < N) ? deg[i] : 0;
  int s = v;
#pragma unroll
  for (int off = 1; off < 64; off <<= 1) s += __shfl_xor(s, off);
  __shared__ int ws[4];
  if (lane == 0) ws[wave] = s;
  __syncthreads();
  if (tid == 0) bsum[blockIdx.x] = ws[0] + ws[1] + ws[2] + ws[3];
}

__global__ void k_scan2(int* __restrict__ bsum, int nb) {
  const int tid = threadIdx.x, lane = tid & 63, wave = tid >> 6;
  int v = (tid < nb) ? bsum[tid] : 0;
  int incl = wave_incl_scan(v, lane);
  __shared__ int ws[4];
  if (lane == 63) ws[wave] = incl;
  __syncthreads();
  int add = 0;
  for (int w = 0; w < wave; ++w) add += ws[w];
  if (tid < nb) bsum[tid] = add + incl - v;  // exclusive
}

__global__ void k_scan3(const int* __restrict__ deg, const int* __restrict__ bexcl, int N,
                        int* __restrict__ offs, int* __restrict__ cursor) {
  const int tid = threadIdx.x, lane = tid & 63, wave = tid >> 6;
  int i = blockIdx.x * 256 + tid;
  int v = (i < N) ? deg[i] : 0;
  int incl = wave_incl_scan(v, lane);
  __shared__ int ws[4];
  if (lane == 63) ws[wave] = incl;
  __syncthreads();
  int add = bexcl[blockIdx.x];
  for (int w = 0; w < wave; ++w) add += ws[w];
  if (i < N) {
    offs[i + 1] = add + incl;
    cursor[i] = add + incl - v;
  }
  if (i == 0) offs[0] = 0;
}

__global__ void k_fill(const int* __restrict__ src, const int* __restrict__ dst, int E,
                       int* __restrict__ cursor, int* __restrict__ csr) {
  int i = blockIdx.x * blockDim.x + threadIdx.x;
  if (i < E) {
    int p = atomicAdd(&cursor[dst[i]], 1);
    csr[p] = src[i];
  }
}

// ---------------- weight precompute ----------------
__global__ void k_softmax(const float* __restrict__ gate, int H,
                          const float* __restrict__ hopw, float* __restrict__ sm) {
  if (blockIdx.x == 0 && threadIdx.x == 0) {
    float mx = -1e30f;
    for (int h = 0; h < H; ++h) mx = fmaxf(mx, gate[h]);
    float s = 0.f;
    for (int h = 0; h < H; ++h) { float e = expf(gate[h] - mx); sm[h] = e; s += e; }
    for (int h = 0; h < H; ++h) sm[h] /= s;
    float m2 = fmaxf(hopw[0], hopw[1]);
    float e0 = expf(hopw[0] - m2), e1 = expf(hopw[1] - m2);
    sm[32] = e0 / (e0 + e1);
    sm[33] = e1 / (e0 + e1);
  }
}

__global__ void k_wbar(const float* __restrict__ Wh_w, const float* __restrict__ Wh_b, int H,
                       float* __restrict__ Wbar, float* __restrict__ bbar) {
  int j = blockIdx.x * 256 + threadIdx.x;
  float s = 0.f;
  for (int h = 0; h < H; ++h) s += Wh_w[h * 65536 + j];
  Wbar[j] = s / (float)H;
  if (j < DFEAT) {
    float b = 0.f;
    for (int h = 0; h < H; ++h) b += Wh_b[h * DFEAT + j];
    bbar[j] = b / (float)H;
  }
}

__global__ void k_wcat(const float* __restrict__ Wp_w, const float* __restrict__ Wp_b,
                       const float* __restrict__ sm, float* __restrict__ Wcat,
                       float* __restrict__ bcat) {
  int j = blockIdx.x * 256 + threadIdx.x;
  Wcat[j] = sm[j >> 13] * Wp_w[j];
  if (j < DFEAT) bcat[j] = sm[j >> 5] * Wp_b[j];
}

__global__ void k_mm(const float* __restrict__ A, const float* __restrict__ B,
                     float* __restrict__ C) {
  int i = blockIdx.x, d = threadIdx.x;
  float c = 0.f;
#pragma unroll 8
  for (int k = 0; k < DFEAT; ++k) c = fmaf(A[i * DFEAT + k], B[k * DFEAT + d], c);
  C[i * DFEAT + d] = c;
}

__global__ void k_cvec(const float* __restrict__ Wcat, const float* __restrict__ W1,
                       const float* __restrict__ bbar, const float* __restrict__ sm,
                       float* __restrict__ c1s, float* __restrict__ c2s) {
  int i = threadIdx.x;
  float s1 = 0.f, s2 = 0.f;
  for (int k = 0; k < DFEAT; ++k) {
    float b = bbar[k];
    s1 = fmaf(Wcat[i * DFEAT + k], b, s1);
    s2 = fmaf(W1[i * DFEAT + k], b, s2);
  }
  float hw0 = sm[32], hw1 = sm[33];
  c1s[i] = (hw0 + hw1) * s1;
  c2s[i] = hw1 * s2;
}

// ---------------- edge pass: one wave per node ----------------
template <bool DOF>
__global__ void k_agg(const float* __restrict__ x, const int* __restrict__ csr,
                      const int* __restrict__ offs, const float* __restrict__ invd,
                      int N, float* __restrict__ out,
                      const float* __restrict__ mask, float* __restrict__ f) {
  int wid = (blockIdx.x * blockDim.x + threadIdx.x) >> 6;
  int lane = threadIdx.x & 63;
  if (wid >= N) return;
  int beg = offs[wid], end = offs[wid + 1];
  float a0 = 0.f, a1 = 0.f, a2 = 0.f, a3 = 0.f, fm = 0.f;
  for (int e = beg; e < end; ++e) {
    int s = csr[e];
    const float4 v = *(reinterpret_cast<const float4*>(x + (size_t)s * DFEAT) + lane);
    a0 += v.x; a1 += v.y; a2 += v.z; a3 += v.w;
    if (DOF) fm += mask[s];
  }
  float w = invd[wid];
  float4 r = make_float4(a0 * w, a1 * w, a2 * w, a3 * w);
  *(reinterpret_cast<float4*>(out + (size_t)wid * DFEAT) + lane) = r;
  if (DOF && lane == 0) f[wid] = fm * w;
}

// ---------------- fused final GEMM: 64x256 tile, 8x8 per thread, in-place on d_out ----
#define PA 68
#define PB 260
__global__ __launch_bounds__(256) void k_final(
    float* out,                     // N x 256, holds m0 on entry (read chunks 0-7, written in epilogue)
    const float* __restrict__ mm0,  // N x 256
    const float* __restrict__ W1, const float* __restrict__ W2,
    const float* __restrict__ sm, const float* __restrict__ mask,
    const float* __restrict__ fbuf, const float* __restrict__ c1s,
    const float* __restrict__ c2s, const float* __restrict__ bcat, int N) {
  __shared__ float As[32 * PA];  // As[k*PA + row], 64 rows
  __shared__ float Bs[32 * PB];  // Bs[k*PB + col], 256 cols (pre-scaled by hw)
  const int tid = threadIdx.x;
  const int tc = tid & 31;  // col group: cols tc*4..+3 and 128+tc*4..+3
  const int tr = tid >> 5;  // row group: rows tr*8..+7
  const int r0 = blockIdx.x * 64;
  const float hw0 = sm[32], hw1 = sm[33];

  float acc[8][8];
#pragma unroll
  for (int i = 0; i < 8; ++i)
#pragma unroll
    for (int j = 0; j < 8; ++j) acc[i][j] = 0.f;

  for (int chunk = 0; chunk < 16; ++chunk) {
    const bool first = chunk < 8;
    const float* Aptr = first ? out : mm0;
    const float* W = first ? W1 : W2;
    const float hw = first ? hw0 : hw1;
    const int kb = (chunk & 7) << 5;

    // stage A: 64 rows x 32 k -> As[k][row]; 512 float4s, 2 per thread
#pragma unroll
    for (int rep = 0; rep < 2; ++rep) {
      const int flat = rep * 256 + tid;
      const int row = flat >> 3;
      const int k4 = (flat & 7) << 2;
      const int gr = r0 + row;
      float4 v = make_float4(0.f, 0.f, 0.f, 0.f);
      if (gr < N) v = *reinterpret_cast<const float4*>(Aptr + (size_t)gr * DFEAT + kb + k4);
      As[(k4 + 0) * PA + row] = v.x;
      As[(k4 + 1) * PA + row] = v.y;
      As[(k4 + 2) * PA + row] = v.z;
      As[(k4 + 3) * PA + row] = v.w;
    }
    // stage B: 256 cols x 32 k -> Bs[k][col] scaled; 2048 float4s, 8 per thread
#pragma unroll
    for (int rep = 0; rep < 8; ++rep) {
      const int flat = rep * 256 + tid;
      const int col = flat >> 3;
      const int k4 = (flat & 7) << 2;
      const float4 v = *reinterpret_cast<const float4*>(W + col * DFEAT + kb + k4);
      Bs[(k4 + 0) * PB + col] = hw * v.x;
      Bs[(k4 + 1) * PB + col] = hw * v.y;
      Bs[(k4 + 2) * PB + col] = hw * v.z;
      Bs[(k4 + 3) * PB + col] = hw * v.w;
    }
    __syncthreads();

#pragma unroll 4
    for (int k = 0; k < 32; ++k) {
      const float4 a0 = *reinterpret_cast<const float4*>(&As[k * PA + tr * 8]);
      const float4 a1 = *reinterpret_cast<const float4*>(&As[k * PA + tr * 8 + 4]);
      const float4 b0 = *reinterpret_cast<const float4*>(&Bs[k * PB + tc * 4]);
      const float4 b1 = *reinterpret_cast<const float4*>(&Bs[k * PB + 128 + tc * 4]);
      const float av[8] = {a0.x, a0.y, a0.z, a0.w, a1.x, a1.y, a1.z, a1.w};
      const float bv[8] = {b0.x, b0.y, b0.z, b0.w, b1.x, b1.y, b1.z, b1.w};
#pragma unroll
      for (int i = 0; i < 8; ++i)
#pragma unroll
        for (int j = 0; j < 8; ++j) acc[i][j] = fmaf(av[i], bv[j], acc[i][j]);
    }
    __syncthreads();
  }

  const int gc0 = tc * 4, gc1 = 128 + tc * 4;
  const float4 c1a = *reinterpret_cast<const float4*>(c1s + gc0);
  const float4 c1b = *reinterpret_cast<const float4*>(c1s + gc1);
  const float4 c2a = *reinterpret_cast<const float4*>(c2s + gc0);
  const float4 c2b = *reinterpret_cast<const float4*>(c2s + gc1);
  const float4 ba = *reinterpret_cast<const float4*>(bcat + gc0);
  const float4 bb = *reinterpret_cast<const float4*>(bcat + gc1);
#pragma unroll
  for (int i = 0; i < 8; ++i) {
    const int gr = r0 + tr * 8 + i;
    if (gr < N) {
      const float mk = mask[gr];
      const float fv = fbuf[gr];
      float4 o0, o1;
      o0.x = acc[i][0] + mk * c1a.x + fv * c2a.x + ba.x;
      o0.y = acc[i][1] + mk * c1a.y + fv * c2a.y + ba.y;
      o0.z = acc[i][2] + mk * c1a.z + fv * c2a.z + ba.z;
      o0.w = acc[i][3] + mk * c1a.w + fv * c2a.w + ba.w;
      o1.x = acc[i][4] + mk * c1b.x + fv * c2b.x + bb.x;
      o1.y = acc[i][5] + mk * c1b.y + fv * c2b.y + bb.y;
      o1.z = acc[i][6] + mk * c1b.z + fv * c2b.z + bb.z;
      o1.w = acc[i][7] + mk * c1b.w + fv * c2b.w + bb.w;
      *reinterpret_cast<float4*>(out + (size_t)gr * DFEAT + gc0) = o0;
      *reinterpret_cast<float4*>(out + (size_t)gr * DFEAT + gc1) = o1;
    }
  }
}

// ---------------- host ----------------
extern "C" void kernel_launch(void* const* d_in, const int* in_sizes, int n_in,
                              void* d_out, int out_size, void* d_ws, size_t ws_size,
                              hipStream_t stream) {
  const float* x    = (const float*)d_in[0];
  const float* Wh_w = (const float*)d_in[1];
  const float* Wh_b = (const float*)d_in[2];
  const float* Wp_w = (const float*)d_in[3];
  const float* Wp_b = (const float*)d_in[4];
  const float* gate = (const float*)d_in[5];
  const float* hopw = (const float*)d_in[6];
  const int* src    = (const int*)d_in[7];
  const int* dst    = (const int*)d_in[8];

  const int H = in_sizes[5];
  const int E = in_sizes[7];
  const int N = in_sizes[0] / DFEAT;
  float* out = (float*)d_out;

  char* w = (char*)d_ws;
  auto take = [&](size_t bytes) -> char* {
    char* p = w;
    w += (bytes + 255) & ~(size_t)255;
    return p;
  };
  float* mm0   = (float*)take((size_t)N * DFEAT * 4);
  int* csr     = (int*)take((size_t)E * 4);
  int* offs    = (int*)take((size_t)(N + 1) * 4);
  int* cursor  = (int*)take((size_t)N * 4);
  int* deg     = (int*)take((size_t)N * 4);
  float* invd  = (float*)take((size_t)N * 4);
  float* mask  = (float*)take((size_t)N * 4);
  float* fbuf  = (float*)take((size_t)N * 4);
  float* Wbar  = (float*)take(65536 * 4);
  float* Wcat  = (float*)take(65536 * 4);
  float* W1    = (float*)take(65536 * 4);
  float* W2    = (float*)take(65536 * 4);
  float* bbar  = (float*)take(256 * 4);
  float* bcat  = (float*)take(256 * 4);
  float* c1s   = (float*)take(256 * 4);
  float* c2s   = (float*)take(256 * 4);
  float* sm    = (float*)take(64 * 4);
  int* bsum    = (int*)take(256 * 4);

  const int nScanBlocks = (N + 255) / 256;  // 196 <= 256

  // graph structure
  hipMemsetAsync(deg, 0, (size_t)N * 4, stream);
  k_deg<<<(E + 255) / 256, 256, 0, stream>>>(dst, E, deg);
  k_scan1<<<nScanBlocks, 256, 0, stream>>>(deg, N, bsum);
  k_scan2<<<1, 256, 0, stream>>>(bsum, nScanBlocks);
  k_scan3<<<nScanBlocks, 256, 0, stream>>>(deg, bsum, N, offs, cursor);
  k_invdeg<<<(N + 255) / 256, 256, 0, stream>>>(deg, N, invd, mask);
  k_fill<<<(E + 255) / 256, 256, 0, stream>>>(src, dst, E, cursor, csr);

  // folded weights
  k_softmax<<<1, 64, 0, stream>>>(gate, H, hopw, sm);
  k_wbar<<<256, 256, 0, stream>>>(Wh_w, Wh_b, H, Wbar, bbar);
  k_wcat<<<256, 256, 0, stream>>>(Wp_w, Wp_b, sm, Wcat, bcat);
  k_mm<<<256, 256, 0, stream>>>(Wcat, Wbar, W1);
  k_mm<<<256, 256, 0, stream>>>(W1, Wbar, W2);
  k_cvec<<<1, 256, 0, stream>>>(Wcat, W1, bbar, sm, c1s, c2s);

  // m0 = meanagg(x) -> d_out ; mm0 = meanagg(m0) (+ f = meanagg(mask))
  const int aggBlocks = (N + 3) / 4;
  k_agg<false><<<aggBlocks, 256, 0, stream>>>(x, csr, offs, invd, N, out, nullptr, nullptr);
  k_agg<true><<<aggBlocks, 256, 0, stream>>>(out, csr, offs, invd, N, mm0, mask, fbuf);

  // out = hw0*m0@W1^T + hw1*mm0@W2^T + mask*c1s + f*c2s + bcat  (in place)
  k_final<<<(N + 63) / 64, 256, 0, stream>>>(out, mm0, W1, W2, sm, mask, fbuf,
                                             c1s, c2s, bcat, N);
}

// Round 3
// 437.493 us; speedup vs baseline: 1.4387x; 1.3647x over previous
//
#include <hip/hip_runtime.h>
#include <math.h>

#define DFEAT 256

typedef short bf16x8 __attribute__((ext_vector_type(8)));
typedef float f32x4 __attribute__((ext_vector_type(4)));

__device__ __forceinline__ unsigned short f2bf(float f) {
  union { float f; unsigned int u; } v;
  v.f = f;
  unsigned int r = v.u + 0x7fff + ((v.u >> 16) & 1);  // RNE
  return (unsigned short)(r >> 16);
}
__device__ __forceinline__ float bf2f(unsigned short b) {
  union { float f; unsigned int u; } v;
  v.u = ((unsigned int)b) << 16;
  return v.f;
}

// ---------------- graph setup ----------------
__global__ void k_deg(const int* __restrict__ dst, int E, int* __restrict__ deg) {
  int i = blockIdx.x * blockDim.x + threadIdx.x;
  if (i < E) atomicAdd(&deg[dst[i]], 1);
}

__global__ void k_invdeg(const int* __restrict__ deg, int N,
                         float* __restrict__ invd, float* __restrict__ mask) {
  int i = blockIdx.x * blockDim.x + threadIdx.x;
  if (i < N) {
    int d = deg[i];
    invd[i] = d > 0 ? 1.0f / (float)d : 0.0f;
    mask[i] = d > 0 ? 1.0f : 0.0f;
  }
}

// ---------------- parallel 3-phase exclusive scan ----------------
__device__ __forceinline__ int wave_incl_scan(int x, int lane) {
#pragma unroll
  for (int off = 1; off < 64; off <<= 1) {
    int t = __shfl_up(x, off);
    if (lane >= off) x += t;
  }
  return x;
}

__global__ void k_scan1(const int* __restrict__ deg, int N, int* __restrict__ bsum) {
  const int tid = threadIdx.x, lane = tid & 63, wave = tid >> 6;
  int i = blockIdx.x * 256 + tid;
  int v = (i < N) ? deg[i] : 0;
  int s = v;
#pragma unroll
  for (int off = 1; off < 64; off <<= 1) s += __shfl_xor(s, off);
  __shared__ int ws[4];
  if (lane == 0) ws[wave] = s;
  __syncthreads();
  if (tid == 0) bsum[blockIdx.x] = ws[0] + ws[1] + ws[2] + ws[3];
}

__global__ void k_scan2(int* __restrict__ bsum, int nb) {
  const int tid = threadIdx.x, lane = tid & 63, wave = tid >> 6;
  int v = (tid < nb) ? bsum[tid] : 0;
  int incl = wave_incl_scan(v, lane);
  __shared__ int ws[4];
  if (lane == 63) ws[wave] = incl;
  __syncthreads();
  int add = 0;
  for (int w = 0; w < wave; ++w) add += ws[w];
  if (tid < nb) bsum[tid] = add + incl - v;  // exclusive
}

__global__ void k_scan3(const int* __restrict__ deg, const int* __restrict__ bexcl, int N,
                        int* __restrict__ offs, int* __restrict__ cursor) {
  const int tid = threadIdx.x, lane = tid & 63, wave = tid >> 6;
  int i = blockIdx.x * 256 + tid;
  int v = (i < N) ? deg[i] : 0;
  int incl = wave_incl_scan(v, lane);
  __shared__ int ws[4];
  if (lane == 63) ws[wave] = incl;
  __syncthreads();
  int add = bexcl[blockIdx.x];
  for (int w = 0; w < wave; ++w) add += ws[w];
  if (i < N) {
    offs[i + 1] = add + incl;
    cursor[i] = add + incl - v;
  }
  if (i == 0) offs[0] = 0;
}

__global__ void k_fill(const int* __restrict__ src, const int* __restrict__ dst, int E,
                       int* __restrict__ cursor, int* __restrict__ csr) {
  int i = blockIdx.x * blockDim.x + threadIdx.x;
  if (i < E) {
    int p = atomicAdd(&cursor[dst[i]], 1);
    csr[p] = src[i];
  }
}

// ---------------- weight precompute ----------------
__global__ void k_softmax(const float* __restrict__ gate, int H,
                          const float* __restrict__ hopw, float* __restrict__ sm) {
  if (blockIdx.x == 0 && threadIdx.x == 0) {
    float mx = -1e30f;
    for (int h = 0; h < H; ++h) mx = fmaxf(mx, gate[h]);
    float s = 0.f;
    for (int h = 0; h < H; ++h) { float e = expf(gate[h] - mx); sm[h] = e; s += e; }
    for (int h = 0; h < H; ++h) sm[h] /= s;
    float m2 = fmaxf(hopw[0], hopw[1]);
    float e0 = expf(hopw[0] - m2), e1 = expf(hopw[1] - m2);
    sm[32] = e0 / (e0 + e1);
    sm[33] = e1 / (e0 + e1);
  }
}

__global__ void k_wbar(const float* __restrict__ Wh_w, const float* __restrict__ Wh_b, int H,
                       float* __restrict__ Wbar, float* __restrict__ bbar) {
  int j = blockIdx.x * 256 + threadIdx.x;
  float s = 0.f;
  for (int h = 0; h < H; ++h) s += Wh_w[h * 65536 + j];
  Wbar[j] = s / (float)H;
  if (j < DFEAT) {
    float b = 0.f;
    for (int h = 0; h < H; ++h) b += Wh_b[h * DFEAT + j];
    bbar[j] = b / (float)H;
  }
}

__global__ void k_wcat(const float* __restrict__ Wp_w, const float* __restrict__ Wp_b,
                       const float* __restrict__ sm, float* __restrict__ Wcat,
                       float* __restrict__ bcat) {
  int j = blockIdx.x * 256 + threadIdx.x;
  Wcat[j] = sm[j >> 13] * Wp_w[j];
  if (j < DFEAT) bcat[j] = sm[j >> 5] * Wp_b[j];
}

__global__ void k_mm(const float* __restrict__ A, const float* __restrict__ B,
                     float* __restrict__ C) {
  int i = blockIdx.x, d = threadIdx.x;
  float c = 0.f;
#pragma unroll 8
  for (int k = 0; k < DFEAT; ++k) c = fmaf(A[i * DFEAT + k], B[k * DFEAT + d], c);
  C[i * DFEAT + d] = c;
}

__global__ void k_cvec(const float* __restrict__ Wcat, const float* __restrict__ W1,
                       const float* __restrict__ bbar, const float* __restrict__ sm,
                       float* __restrict__ c1s, float* __restrict__ c2s) {
  int i = threadIdx.x;
  float s1 = 0.f, s2 = 0.f;
  for (int k = 0; k < DFEAT; ++k) {
    float b = bbar[k];
    s1 = fmaf(Wcat[i * DFEAT + k], b, s1);
    s2 = fmaf(W1[i * DFEAT + k], b, s2);
  }
  float hw0 = sm[32], hw1 = sm[33];
  c1s[i] = (hw0 + hw1) * s1;
  c2s[i] = hw1 * s2;
}

// pack B for MFMA: Bpk[((t*256 + c)*4 + g)*8 + j] = hw_t * W_t[c][ (t&7)*32 + g*8 + j ]
__global__ void k_bprep(const float* __restrict__ W1, const float* __restrict__ W2,
                        const float* __restrict__ sm, unsigned short* __restrict__ Bpk) {
  int flat = blockIdx.x * 256 + threadIdx.x;  // 0..16383
  int t = flat >> 10;
  int c = (flat >> 2) & 255;
  int g = flat & 3;
  const float* W = (t < 8) ? W1 : W2;
  const float hw = (t < 8) ? sm[32] : sm[33];
  const float* p = W + c * DFEAT + (t & 7) * 32 + g * 8;
  unsigned short o[8];
#pragma unroll
  for (int j = 0; j < 8; ++j) o[j] = f2bf(hw * p[j]);
  ulonglong2* dstp = reinterpret_cast<ulonglong2*>(Bpk + (size_t)flat * 8);
  *dstp = *reinterpret_cast<ulonglong2*>(o);
}

// x fp32 -> bf16
__global__ void k_xbf(const float* __restrict__ x, unsigned short* __restrict__ xbf, int n4) {
  int i = blockIdx.x * blockDim.x + threadIdx.x;
  if (i < n4) {
    float4 v = reinterpret_cast<const float4*>(x)[i];
    ushort4 o;
    o.x = f2bf(v.x); o.y = f2bf(v.y); o.z = f2bf(v.z); o.w = f2bf(v.w);
    reinterpret_cast<ushort4*>(xbf)[i] = o;
  }
}

// ---------------- edge pass (bf16 in / bf16 out): one wave per node ----------------
template <bool DOF>
__global__ void k_aggb(const unsigned short* __restrict__ xbf, const int* __restrict__ csr,
                       const int* __restrict__ offs, const float* __restrict__ invd,
                       int N, unsigned short* __restrict__ outbf,
                       const float* __restrict__ mask, float* __restrict__ f) {
  int wid = (blockIdx.x * blockDim.x + threadIdx.x) >> 6;
  int lane = threadIdx.x & 63;
  if (wid >= N) return;
  int beg = offs[wid], end = offs[wid + 1];
  float a0 = 0.f, a1 = 0.f, a2 = 0.f, a3 = 0.f, fm = 0.f;
  for (int e = beg; e < end; ++e) {
    int s = csr[e];
    const ushort4 v = *(reinterpret_cast<const ushort4*>(xbf + (size_t)s * DFEAT) + lane);
    a0 += bf2f(v.x); a1 += bf2f(v.y); a2 += bf2f(v.z); a3 += bf2f(v.w);
    if (DOF) fm += mask[s];
  }
  float w = invd[wid];
  ushort4 r;
  r.x = f2bf(a0 * w); r.y = f2bf(a1 * w); r.z = f2bf(a2 * w); r.w = f2bf(a3 * w);
  *(reinterpret_cast<ushort4*>(outbf + (size_t)wid * DFEAT) + lane) = r;
  if (DOF && lane == 0) f[wid] = fm * w;
}

// ---------------- final GEMM via MFMA bf16 ----------------
// out[n][j] = sum_k A[n][k]*B[k][j] + mask[n]*c1s[j] + fbuf[n]*c2s[j] + bcat[j]
// A = [m0bf | mm0bf] (N x 512 bf16), B prepacked (hw scales folded in).
// block = 256 thr = 4 waves; wave w owns rows r0+w*16..+15, all 256 cols.
__global__ __launch_bounds__(256) void k_final_mfma(
    const unsigned short* __restrict__ m0bf, const unsigned short* __restrict__ mm0bf,
    const unsigned short* __restrict__ Bpk,
    const float* __restrict__ mask, const float* __restrict__ fbuf,
    const float* __restrict__ c1s, const float* __restrict__ c2s,
    const float* __restrict__ bcat, float* __restrict__ out, int N) {
  const int tid = threadIdx.x;
  const int lane = tid & 63;
  const int wave = tid >> 6;
  const int r0 = blockIdx.x * 64 + wave * 16;
  const int lr = lane & 15;  // A-row / D-col within tile
  const int lg = lane >> 4;  // k-group

  f32x4 acc[16];
#pragma unroll
  for (int c = 0; c < 16; ++c) acc[c] = (f32x4){0.f, 0.f, 0.f, 0.f};

  const int arow = r0 + lr;
  const bool rowok = arow < N;
  const size_t abase = (size_t)arow * DFEAT + lg * 8;

#pragma unroll
  for (int t = 0; t < 16; ++t) {
    const unsigned short* As = (t < 8) ? m0bf : mm0bf;
    const int kb = (t & 7) * 32;
    bf16x8 af = (bf16x8){0, 0, 0, 0, 0, 0, 0, 0};
    if (rowok) af = *reinterpret_cast<const bf16x8*>(As + abase + kb);
#pragma unroll
    for (int c = 0; c < 16; ++c) {
      const int boff = (((t << 8) + (c << 4) + lr) << 2) + lg;  // /8 elements
      const bf16x8 bf = *reinterpret_cast<const bf16x8*>(Bpk + ((size_t)boff << 3));
      acc[c] = __builtin_amdgcn_mfma_f32_16x16x32_bf16(af, bf, acc[c], 0, 0, 0);
    }
  }

  // epilogue: lane covers rows rbase..rbase+3 (D row = lg*4+i), col = c*16+lr
  const int rbase = r0 + lg * 4;
  float mk[4], fv[4];
#pragma unroll
  for (int i = 0; i < 4; ++i) {
    int r = rbase + i;
    mk[i] = (r < N) ? mask[r] : 0.f;
    fv[i] = (r < N) ? fbuf[r] : 0.f;
  }
#pragma unroll
  for (int c = 0; c < 16; ++c) {
    const int col = c * 16 + lr;
    const float c1 = c1s[col], c2 = c2s[col], bc = bcat[col];
#pragma unroll
    for (int i = 0; i < 4; ++i) {
      const int r = rbase + i;
      if (r < N) out[(size_t)r * DFEAT + col] = acc[c][i] + mk[i] * c1 + fv[i] * c2 + bc;
    }
  }
}

// ---------------- host ----------------
extern "C" void kernel_launch(void* const* d_in, const int* in_sizes, int n_in,
                              void* d_out, int out_size, void* d_ws, size_t ws_size,
                              hipStream_t stream) {
  const float* x    = (const float*)d_in[0];
  const float* Wh_w = (const float*)d_in[1];
  const float* Wh_b = (const float*)d_in[2];
  const float* Wp_w = (const float*)d_in[3];
  const float* Wp_b = (const float*)d_in[4];
  const float* gate = (const float*)d_in[5];
  const float* hopw = (const float*)d_in[6];
  const int* src    = (const int*)d_in[7];
  const int* dst    = (const int*)d_in[8];

  const int H = in_sizes[5];
  const int E = in_sizes[7];
  const int N = in_sizes[0] / DFEAT;
  float* out = (float*)d_out;

  char* w = (char*)d_ws;
  auto take = [&](size_t bytes) -> char* {
    char* p = w;
    w += (bytes + 255) & ~(size_t)255;
    return p;
  };
  unsigned short* xbf   = (unsigned short*)take((size_t)N * DFEAT * 2);
  unsigned short* m0bf  = (unsigned short*)take((size_t)N * DFEAT * 2);
  unsigned short* mm0bf = (unsigned short*)take((size_t)N * DFEAT * 2);
  unsigned short* Bpk   = (unsigned short*)take((size_t)512 * 256 * 2);
  int* csr     = (int*)take((size_t)E * 4);
  int* offs    = (int*)take((size_t)(N + 1) * 4);
  int* cursor  = (int*)take((size_t)N * 4);
  int* deg     = (int*)take((size_t)N * 4);
  float* invd  = (float*)take((size_t)N * 4);
  float* mask  = (float*)take((size_t)N * 4);
  float* fbuf  = (float*)take((size_t)N * 4);
  float* Wbar  = (float*)take(65536 * 4);
  float* Wcat  = (float*)take(65536 * 4);
  float* W1    = (float*)take(65536 * 4);
  float* W2    = (float*)take(65536 * 4);
  float* bbar  = (float*)take(256 * 4);
  float* bcat  = (float*)take(256 * 4);
  float* c1s   = (float*)take(256 * 4);
  float* c2s   = (float*)take(256 * 4);
  float* sm    = (float*)take(64 * 4);
  int* bsum    = (int*)take(256 * 4);

  const int nScanBlocks = (N + 255) / 256;

  // graph structure
  hipMemsetAsync(deg, 0, (size_t)N * 4, stream);
  k_deg<<<(E + 255) / 256, 256, 0, stream>>>(dst, E, deg);
  k_scan1<<<nScanBlocks, 256, 0, stream>>>(deg, N, bsum);
  k_scan2<<<1, 256, 0, stream>>>(bsum, nScanBlocks);
  k_scan3<<<nScanBlocks, 256, 0, stream>>>(deg, bsum, N, offs, cursor);
  k_invdeg<<<(N + 255) / 256, 256, 0, stream>>>(deg, N, invd, mask);
  k_fill<<<(E + 255) / 256, 256, 0, stream>>>(src, dst, E, cursor, csr);

  // x -> bf16 (independent of graph kernels but same stream)
  k_xbf<<<(N * DFEAT / 4 + 255) / 256, 256, 0, stream>>>(x, xbf, N * DFEAT / 4);

  // folded weights
  k_softmax<<<1, 64, 0, stream>>>(gate, H, hopw, sm);
  k_wbar<<<256, 256, 0, stream>>>(Wh_w, Wh_b, H, Wbar, bbar);
  k_wcat<<<256, 256, 0, stream>>>(Wp_w, Wp_b, sm, Wcat, bcat);
  k_mm<<<256, 256, 0, stream>>>(Wcat, Wbar, W1);
  k_mm<<<256, 256, 0, stream>>>(W1, Wbar, W2);
  k_cvec<<<1, 256, 0, stream>>>(Wcat, W1, bbar, sm, c1s, c2s);
  k_bprep<<<64, 256, 0, stream>>>(W1, W2, sm, Bpk);

  // m0bf = meanagg(xbf) ; mm0bf = meanagg(m0bf) (+ f = meanagg(mask))
  const int aggBlocks = (N + 3) / 4;
  k_aggb<false><<<aggBlocks, 256, 0, stream>>>(xbf, csr, offs, invd, N, m0bf, nullptr, nullptr);
  k_aggb<true><<<aggBlocks, 256, 0, stream>>>(m0bf, csr, offs, invd, N, mm0bf, mask, fbuf);

  // out = [m0|mm0] @ Bpk + mask*c1s + f*c2s + bcat
  k_final_mfma<<<(N + 63) / 64, 256, 0, stream>>>(m0bf, mm0bf, Bpk, mask, fbuf,
                                                  c1s, c2s, bcat, out, N);
}

// Round 4
// 376.734 us; speedup vs baseline: 1.6707x; 1.1613x over previous
//
#include <hip/hip_runtime.h>
#include <math.h>

#define DFEAT 256

typedef short bf16x8 __attribute__((ext_vector_type(8)));
typedef float f32x4 __attribute__((ext_vector_type(4)));

__device__ __forceinline__ unsigned short f2bf(float f) {
  union { float f; unsigned int u; } v;
  v.f = f;
  unsigned int r = v.u + 0x7fff + ((v.u >> 16) & 1);  // RNE
  return (unsigned short)(r >> 16);
}
__device__ __forceinline__ float bf2f(unsigned short b) {
  union { float f; unsigned int u; } v;
  v.u = ((unsigned int)b) << 16;
  return v.f;
}

// ---------------- graph setup ----------------
__global__ void k_deg(const int* __restrict__ dst, int E, int* __restrict__ deg) {
  int i = blockIdx.x * blockDim.x + threadIdx.x;
  if (i < E) atomicAdd(&deg[dst[i]], 1);
}

__global__ void k_invdeg(const int* __restrict__ deg, int N,
                         float* __restrict__ invd, float* __restrict__ mask) {
  int i = blockIdx.x * blockDim.x + threadIdx.x;
  if (i < N) {
    int d = deg[i];
    invd[i] = d > 0 ? 1.0f / (float)d : 0.0f;
    mask[i] = d > 0 ? 1.0f : 0.0f;
  }
}

// ---------------- parallel 3-phase exclusive scan ----------------
__device__ __forceinline__ int wave_incl_scan(int x, int lane) {
#pragma unroll
  for (int off = 1; off < 64; off <<= 1) {
    int t = __shfl_up(x, off);
    if (lane >= off) x += t;
  }
  return x;
}

__global__ void k_scan1(const int* __restrict__ deg, int N, int* __restrict__ bsum) {
  const int tid = threadIdx.x, lane = tid & 63, wave = tid >> 6;
  int i = blockIdx.x * 256 + tid;
  int v = (i < N) ? deg[i] : 0;
  int s = v;
#pragma unroll
  for (int off = 1; off < 64; off <<= 1) s += __shfl_xor(s, off);
  __shared__ int ws[4];
  if (lane == 0) ws[wave] = s;
  __syncthreads();
  if (tid == 0) bsum[blockIdx.x] = ws[0] + ws[1] + ws[2] + ws[3];
}

__global__ void k_scan2(int* __restrict__ bsum, int nb) {
  const int tid = threadIdx.x, lane = tid & 63, wave = tid >> 6;
  int v = (tid < nb) ? bsum[tid] : 0;
  int incl = wave_incl_scan(v, lane);
  __shared__ int ws[4];
  if (lane == 63) ws[wave] = incl;
  __syncthreads();
  int add = 0;
  for (int w = 0; w < wave; ++w) add += ws[w];
  if (tid < nb) bsum[tid] = add + incl - v;  // exclusive
}

__global__ void k_scan3(const int* __restrict__ deg, const int* __restrict__ bexcl, int N,
                        int* __restrict__ offs, int* __restrict__ cursor) {
  const int tid = threadIdx.x, lane = tid & 63, wave = tid >> 6;
  int i = blockIdx.x * 256 + tid;
  int v = (i < N) ? deg[i] : 0;
  int incl = wave_incl_scan(v, lane);
  __shared__ int ws[4];
  if (lane == 63) ws[wave] = incl;
  __syncthreads();
  int add = bexcl[blockIdx.x];
  for (int w = 0; w < wave; ++w) add += ws[w];
  if (i < N) {
    offs[i + 1] = add + incl;
    cursor[i] = add + incl - v;
  }
  if (i == 0) offs[0] = 0;
}

__global__ void k_fill(const int* __restrict__ src, const int* __restrict__ dst, int E,
                       int* __restrict__ cursor, int* __restrict__ csr) {
  int i = blockIdx.x * blockDim.x + threadIdx.x;
  if (i < E) {
    int p = atomicAdd(&cursor[dst[i]], 1);
    csr[p] = src[i];
  }
}

// ---------------- weight precompute ----------------
__global__ void k_softmax(const float* __restrict__ gate, int H,
                          const float* __restrict__ hopw, float* __restrict__ sm) {
  if (blockIdx.x == 0 && threadIdx.x == 0) {
    float mx = -1e30f;
    for (int h = 0; h < H; ++h) mx = fmaxf(mx, gate[h]);
    float s = 0.f;
    for (int h = 0; h < H; ++h) { float e = expf(gate[h] - mx); sm[h] = e; s += e; }
    for (int h = 0; h < H; ++h) sm[h] /= s;
    float m2 = fmaxf(hopw[0], hopw[1]);
    float e0 = expf(hopw[0] - m2), e1 = expf(hopw[1] - m2);
    sm[32] = e0 / (e0 + e1);
    sm[33] = e1 / (e0 + e1);
  }
}

__global__ void k_wbar(const float* __restrict__ Wh_w, const float* __restrict__ Wh_b, int H,
                       float* __restrict__ Wbar, float* __restrict__ bbar) {
  int j = blockIdx.x * 256 + threadIdx.x;
  float s = 0.f;
  for (int h = 0; h < H; ++h) s += Wh_w[h * 65536 + j];
  Wbar[j] = s / (float)H;
  if (j < DFEAT) {
    float b = 0.f;
    for (int h = 0; h < H; ++h) b += Wh_b[h * DFEAT + j];
    bbar[j] = b / (float)H;
  }
}

__global__ void k_wcat(const float* __restrict__ Wp_w, const float* __restrict__ Wp_b,
                       const float* __restrict__ sm, float* __restrict__ Wcat,
                       float* __restrict__ bcat) {
  int j = blockIdx.x * 256 + threadIdx.x;
  Wcat[j] = sm[j >> 13] * Wp_w[j];
  if (j < DFEAT) bcat[j] = sm[j >> 5] * Wp_b[j];
}

__global__ void k_mm(const float* __restrict__ A, const float* __restrict__ B,
                     float* __restrict__ C) {
  int i = blockIdx.x, d = threadIdx.x;
  float c = 0.f;
#pragma unroll 8
  for (int k = 0; k < DFEAT; ++k) c = fmaf(A[i * DFEAT + k], B[k * DFEAT + d], c);
  C[i * DFEAT + d] = c;
}

__global__ void k_cvec(const float* __restrict__ Wcat, const float* __restrict__ W1,
                       const float* __restrict__ bbar, const float* __restrict__ sm,
                       float* __restrict__ c1s, float* __restrict__ c2s) {
  int i = threadIdx.x;
  float s1 = 0.f, s2 = 0.f;
  for (int k = 0; k < DFEAT; ++k) {
    float b = bbar[k];
    s1 = fmaf(Wcat[i * DFEAT + k], b, s1);
    s2 = fmaf(W1[i * DFEAT + k], b, s2);
  }
  float hw0 = sm[32], hw1 = sm[33];
  c1s[i] = (hw0 + hw1) * s1;
  c2s[i] = hw1 * s2;
}

// pack B for MFMA, lane-linear chunks:
// flat = t*1024 + c*64 + chunk, chunk = lane = lg*16 + lr
// content: hw_t * W_t[col = c*16+lr][(t&7)*32 + lg*8 + j], j=0..7
__global__ void k_bprep(const float* __restrict__ W1, const float* __restrict__ W2,
                        const float* __restrict__ sm, unsigned short* __restrict__ Bpk) {
  int flat = blockIdx.x * 256 + threadIdx.x;  // 0..16383
  int t = flat >> 10;
  int c = (flat >> 6) & 15;
  int chunk = flat & 63;
  int lr = chunk & 15;
  int lg = chunk >> 4;
  const float* W = (t < 8) ? W1 : W2;
  const float hw = (t < 8) ? sm[32] : sm[33];
  const float* p = W + (c * 16 + lr) * DFEAT + (t & 7) * 32 + lg * 8;
  unsigned short o[8];
#pragma unroll
  for (int j = 0; j < 8; ++j) o[j] = f2bf(hw * p[j]);
  ulonglong2* dstp = reinterpret_cast<ulonglong2*>(Bpk + (size_t)flat * 8);
  *dstp = *reinterpret_cast<ulonglong2*>(o);
}

// x fp32 -> bf16
__global__ void k_xbf(const float* __restrict__ x, unsigned short* __restrict__ xbf, int n4) {
  int i = blockIdx.x * blockDim.x + threadIdx.x;
  if (i < n4) {
    float4 v = reinterpret_cast<const float4*>(x)[i];
    ushort4 o;
    o.x = f2bf(v.x); o.y = f2bf(v.y); o.z = f2bf(v.z); o.w = f2bf(v.w);
    reinterpret_cast<ushort4*>(xbf)[i] = o;
  }
}

// ---------------- edge pass: one wave per node, 2 edges per iteration ----------------
// half-wave (32 lanes x 16B) covers one 512B row; halves combined by shfl_xor(32).
template <bool DOF>
__global__ void k_aggb2(const unsigned short* __restrict__ xbf, const int* __restrict__ csr,
                        const int* __restrict__ offs, const float* __restrict__ invd,
                        int N, unsigned short* __restrict__ outbf,
                        const float* __restrict__ mask, float* __restrict__ f) {
  int wid = (blockIdx.x * blockDim.x + threadIdx.x) >> 6;
  int lane = threadIdx.x & 63;
  if (wid >= N) return;
  const int half = lane >> 5, l5 = lane & 31;
  const int beg = offs[wid], end = offs[wid + 1];
  float a[8] = {0.f, 0.f, 0.f, 0.f, 0.f, 0.f, 0.f, 0.f};
  float fm = 0.f;
  for (int e = beg + half; e < end; e += 2) {
    const int s = csr[e];
    const uint4 q = *reinterpret_cast<const uint4*>(xbf + (size_t)s * DFEAT + l5 * 8);
    a[0] += bf2f((unsigned short)(q.x & 0xffff));
    a[1] += bf2f((unsigned short)(q.x >> 16));
    a[2] += bf2f((unsigned short)(q.y & 0xffff));
    a[3] += bf2f((unsigned short)(q.y >> 16));
    a[4] += bf2f((unsigned short)(q.z & 0xffff));
    a[5] += bf2f((unsigned short)(q.z >> 16));
    a[6] += bf2f((unsigned short)(q.w & 0xffff));
    a[7] += bf2f((unsigned short)(q.w >> 16));
    if (DOF) fm += mask[s];
  }
#pragma unroll
  for (int j = 0; j < 8; ++j) a[j] += __shfl_xor(a[j], 32);
  const float w = invd[wid];
  if (lane < 32) {
    uint4 r;
    r.x = (unsigned)f2bf(a[0] * w) | ((unsigned)f2bf(a[1] * w) << 16);
    r.y = (unsigned)f2bf(a[2] * w) | ((unsigned)f2bf(a[3] * w) << 16);
    r.z = (unsigned)f2bf(a[4] * w) | ((unsigned)f2bf(a[5] * w) << 16);
    r.w = (unsigned)f2bf(a[6] * w) | ((unsigned)f2bf(a[7] * w) << 16);
    *reinterpret_cast<uint4*>(outbf + (size_t)wid * DFEAT + l5 * 8) = r;
  }
  if (DOF) {
    fm += __shfl_xor(fm, 32);
    if (lane == 0) f[wid] = fm * w;
  }
}

// ---------------- final GEMM via MFMA bf16, LDS-staged B ----------------
// block = 256 thr = 4 waves, 64 rows x 256 cols; wave (rg,cg): rows rg*32..+31, cols cg*128..+127.
// B t-slice (16KB) double-buffered in LDS; Bpk is lane-linear so ds_read is conflict-free.
__global__ __launch_bounds__(256) void k_final_mfma(
    const unsigned short* __restrict__ m0bf, const unsigned short* __restrict__ mm0bf,
    const unsigned short* __restrict__ Bpk,
    const float* __restrict__ mask, const float* __restrict__ fbuf,
    const float* __restrict__ c1s, const float* __restrict__ c2s,
    const float* __restrict__ bcat, float* __restrict__ out, int N) {
  __shared__ uint4 Bs[2][1024];  // 2 x 16 KB
  const int tid = threadIdx.x;
  const int lane = tid & 63;
  const int wave = tid >> 6;
  const int lr = lane & 15;
  const int lg = lane >> 4;
  const int cg = wave & 1;   // col half (128 cols)
  const int rg = wave >> 1;  // row half (32 rows)
  const int r0 = blockIdx.x * 64 + rg * 32;
  const uint4* Bv = reinterpret_cast<const uint4*>(Bpk);

  f32x4 acc[2][8];
#pragma unroll
  for (int fr = 0; fr < 2; ++fr)
#pragma unroll
    for (int c = 0; c < 8; ++c) acc[fr][c] = (f32x4){0.f, 0.f, 0.f, 0.f};

  const int arow0 = r0 + lr;
  const int arow1 = r0 + 16 + lr;
  const bool ok0 = arow0 < N, ok1 = arow1 < N;

  uint4 g[4];
#pragma unroll
  for (int i = 0; i < 4; ++i) g[i] = Bv[i * 256 + tid];  // slice t=0

  for (int t = 0; t < 16; ++t) {
    const int b = t & 1;
#pragma unroll
    for (int i = 0; i < 4; ++i) Bs[b][i * 256 + tid] = g[i];
    if (t < 15) {
#pragma unroll
      for (int i = 0; i < 4; ++i) g[i] = Bv[(t + 1) * 1024 + i * 256 + tid];
    }
    __syncthreads();

    const unsigned short* As = (t < 8) ? m0bf : mm0bf;
    const int kb = (t & 7) * 32 + lg * 8;
    bf16x8 af0 = (bf16x8){0, 0, 0, 0, 0, 0, 0, 0};
    bf16x8 af1 = (bf16x8){0, 0, 0, 0, 0, 0, 0, 0};
    if (ok0) af0 = *reinterpret_cast<const bf16x8*>(As + (size_t)arow0 * DFEAT + kb);
    if (ok1) af1 = *reinterpret_cast<const bf16x8*>(As + (size_t)arow1 * DFEAT + kb);
#pragma unroll
    for (int c = 0; c < 8; ++c) {
      const int ca = cg * 8 + c;
      const bf16x8 bf = *reinterpret_cast<const bf16x8*>(&Bs[b][ca * 64 + lane]);
      acc[0][c] = __builtin_amdgcn_mfma_f32_16x16x32_bf16(af0, bf, acc[0][c], 0, 0, 0);
      acc[1][c] = __builtin_amdgcn_mfma_f32_16x16x32_bf16(af1, bf, acc[1][c], 0, 0, 0);
    }
    // dbuf: next iter writes the other buffer; safe with one barrier per iter
  }

  // epilogue: row = r0 + fr*16 + lg*4 + i, col = cg*128 + c*16 + lr
  float c1v[8], c2v[8], bcv[8];
#pragma unroll
  for (int c = 0; c < 8; ++c) {
    const int col = cg * 128 + c * 16 + lr;
    c1v[c] = c1s[col]; c2v[c] = c2s[col]; bcv[c] = bcat[col];
  }
#pragma unroll
  for (int fr = 0; fr < 2; ++fr) {
#pragma unroll
    for (int i = 0; i < 4; ++i) {
      const int r = r0 + fr * 16 + lg * 4 + i;
      if (r < N) {
        const float mk = mask[r];
        const float fv = fbuf[r];
        float* orow = out + (size_t)r * DFEAT + cg * 128 + lr;
#pragma unroll
        for (int c = 0; c < 8; ++c)
          orow[c * 16] = acc[fr][c][i] + mk * c1v[c] + fv * c2v[c] + bcv[c];
      }
    }
  }
}

// ---------------- host ----------------
extern "C" void kernel_launch(void* const* d_in, const int* in_sizes, int n_in,
                              void* d_out, int out_size, void* d_ws, size_t ws_size,
                              hipStream_t stream) {
  const float* x    = (const float*)d_in[0];
  const float* Wh_w = (const float*)d_in[1];
  const float* Wh_b = (const float*)d_in[2];
  const float* Wp_w = (const float*)d_in[3];
  const float* Wp_b = (const float*)d_in[4];
  const float* gate = (const float*)d_in[5];
  const float* hopw = (const float*)d_in[6];
  const int* src    = (const int*)d_in[7];
  const int* dst    = (const int*)d_in[8];

  const int H = in_sizes[5];
  const int E = in_sizes[7];
  const int N = in_sizes[0] / DFEAT;
  float* out = (float*)d_out;

  char* w = (char*)d_ws;
  auto take = [&](size_t bytes) -> char* {
    char* p = w;
    w += (bytes + 255) & ~(size_t)255;
    return p;
  };
  unsigned short* xbf   = (unsigned short*)take((size_t)N * DFEAT * 2);
  unsigned short* m0bf  = (unsigned short*)take((size_t)N * DFEAT * 2);
  unsigned short* mm0bf = (unsigned short*)take((size_t)N * DFEAT * 2);
  unsigned short* Bpk   = (unsigned short*)take((size_t)512 * 256 * 2);
  int* csr     = (int*)take((size_t)E * 4);
  int* offs    = (int*)take((size_t)(N + 1) * 4);
  int* cursor  = (int*)take((size_t)N * 4);
  int* deg     = (int*)take((size_t)N * 4);
  float* invd  = (float*)take((size_t)N * 4);
  float* mask  = (float*)take((size_t)N * 4);
  float* fbuf  = (float*)take((size_t)N * 4);
  float* Wbar  = (float*)take(65536 * 4);
  float* Wcat  = (float*)take(65536 * 4);
  float* W1    = (float*)take(65536 * 4);
  float* W2    = (float*)take(65536 * 4);
  float* bbar  = (float*)take(256 * 4);
  float* bcat  = (float*)take(256 * 4);
  float* c1s   = (float*)take(256 * 4);
  float* c2s   = (float*)take(256 * 4);
  float* sm    = (float*)take(64 * 4);
  int* bsum    = (int*)take(256 * 4);

  const int nScanBlocks = (N + 255) / 256;

  // graph structure
  hipMemsetAsync(deg, 0, (size_t)N * 4, stream);
  k_deg<<<(E + 255) / 256, 256, 0, stream>>>(dst, E, deg);
  k_scan1<<<nScanBlocks, 256, 0, stream>>>(deg, N, bsum);
  k_scan2<<<1, 256, 0, stream>>>(bsum, nScanBlocks);
  k_scan3<<<nScanBlocks, 256, 0, stream>>>(deg, bsum, N, offs, cursor);
  k_invdeg<<<(N + 255) / 256, 256, 0, stream>>>(deg, N, invd, mask);
  k_fill<<<(E + 255) / 256, 256, 0, stream>>>(src, dst, E, cursor, csr);

  // x -> bf16
  k_xbf<<<(N * DFEAT / 4 + 255) / 256, 256, 0, stream>>>(x, xbf, N * DFEAT / 4);

  // folded weights
  k_softmax<<<1, 64, 0, stream>>>(gate, H, hopw, sm);
  k_wbar<<<256, 256, 0, stream>>>(Wh_w, Wh_b, H, Wbar, bbar);
  k_wcat<<<256, 256, 0, stream>>>(Wp_w, Wp_b, sm, Wcat, bcat);
  k_mm<<<256, 256, 0, stream>>>(Wcat, Wbar, W1);
  k_mm<<<256, 256, 0, stream>>>(W1, Wbar, W2);
  k_cvec<<<1, 256, 0, stream>>>(Wcat, W1, bbar, sm, c1s, c2s);
  k_bprep<<<64, 256, 0, stream>>>(W1, W2, sm, Bpk);

  // m0bf = meanagg(xbf) ; mm0bf = meanagg(m0bf) (+ f = meanagg(mask))
  const int aggBlocks = (N + 3) / 4;
  k_aggb2<false><<<aggBlocks, 256, 0, stream>>>(xbf, csr, offs, invd, N, m0bf, nullptr, nullptr);
  k_aggb2<true><<<aggBlocks, 256, 0, stream>>>(m0bf, csr, offs, invd, N, mm0bf, mask, fbuf);

  // out = [m0|mm0] @ Bpk + mask*c1s + f*c2s + bcat
  k_final_mfma<<<(N + 63) / 64, 256, 0, stream>>>(m0bf, mm0bf, Bpk, mask, fbuf,
                                                  c1s, c2s, bcat, out, N);
}

// Round 6
// 355.810 us; speedup vs baseline: 1.7690x; 1.0588x over previous
//
#include <hip/hip_runtime.h>
#include <math.h>

#define DFEAT 256

typedef short bf16x8 __attribute__((ext_vector_type(8)));
typedef float f32x4 __attribute__((ext_vector_type(4)));

__device__ __forceinline__ unsigned short f2bf(float f) {
  union { float f; unsigned int u; } v;
  v.f = f;
  unsigned int r = v.u + 0x7fff + ((v.u >> 16) & 1);  // RNE
  return (unsigned short)(r >> 16);
}
__device__ __forceinline__ float bf2f(unsigned short b) {
  union { float f; unsigned int u; } v;
  v.u = ((unsigned int)b) << 16;
  return v.f;
}

// ---------------- graph setup ----------------
__global__ void k_deg(const int* __restrict__ dst, int E, int* __restrict__ deg) {
  int i = blockIdx.x * blockDim.x + threadIdx.x;
  if (i < E) atomicAdd(&deg[dst[i]], 1);
}

// ---------------- parallel 3-phase exclusive scan ----------------
__device__ __forceinline__ int wave_incl_scan(int x, int lane) {
#pragma unroll
  for (int off = 1; off < 64; off <<= 1) {
    int t = __shfl_up(x, off);
    if (lane >= off) x += t;
  }
  return x;
}

__global__ void k_scan1(const int* __restrict__ deg, int N, int* __restrict__ bsum) {
  const int tid = threadIdx.x, lane = tid & 63, wave = tid >> 6;
  int i = blockIdx.x * 256 + tid;
  int v = (i < N) ? deg[i] : 0;
  int s = v;
#pragma unroll
  for (int off = 1; off < 64; off <<= 1) s += __shfl_xor(s, off);
  __shared__ int ws[4];
  if (lane == 0) ws[wave] = s;
  __syncthreads();
  if (tid == 0) bsum[blockIdx.x] = ws[0] + ws[1] + ws[2] + ws[3];
}

__global__ void k_scan2(int* __restrict__ bsum, int nb) {
  const int tid = threadIdx.x, lane = tid & 63, wave = tid >> 6;
  int v = (tid < nb) ? bsum[tid] : 0;
  int incl = wave_incl_scan(v, lane);
  __shared__ int ws[4];
  if (lane == 63) ws[wave] = incl;
  __syncthreads();
  int add = 0;
  for (int w = 0; w < wave; ++w) add += ws[w];
  if (tid < nb) bsum[tid] = add + incl - v;  // exclusive
}

// scan3 + invdeg/mask fused
__global__ void k_scan3(const int* __restrict__ deg, const int* __restrict__ bexcl, int N,
                        int* __restrict__ offs, int* __restrict__ cursor,
                        float* __restrict__ invd, float* __restrict__ mask) {
  const int tid = threadIdx.x, lane = tid & 63, wave = tid >> 6;
  int i = blockIdx.x * 256 + tid;
  int v = (i < N) ? deg[i] : 0;
  int incl = wave_incl_scan(v, lane);
  __shared__ int ws[4];
  if (lane == 63) ws[wave] = incl;
  __syncthreads();
  int add = bexcl[blockIdx.x];
  for (int w = 0; w < wave; ++w) add += ws[w];
  if (i < N) {
    offs[i + 1] = add + incl;
    cursor[i] = add + incl - v;
    invd[i] = v > 0 ? 1.0f / (float)v : 0.0f;
    mask[i] = v > 0 ? 1.0f : 0.0f;
  }
  if (i == 0) offs[0] = 0;
}

__global__ void k_fill(const int* __restrict__ src, const int* __restrict__ dst, int E,
                       int* __restrict__ cursor, int* __restrict__ csr) {
  int i = blockIdx.x * blockDim.x + threadIdx.x;
  if (i < E) {
    int p = atomicAdd(&cursor[dst[i]], 1);
    csr[p] = src[i];
  }
}

// ---------------- weight precompute ----------------
__global__ void k_softmax(const float* __restrict__ gate, int H,
                          const float* __restrict__ hopw, float* __restrict__ sm) {
  if (blockIdx.x == 0 && threadIdx.x == 0) {
    float mx = -1e30f;
    for (int h = 0; h < H; ++h) mx = fmaxf(mx, gate[h]);
    float s = 0.f;
    for (int h = 0; h < H; ++h) { float e = expf(gate[h] - mx); sm[h] = e; s += e; }
    for (int h = 0; h < H; ++h) sm[h] /= s;
    float m2 = fmaxf(hopw[0], hopw[1]);
    float e0 = expf(hopw[0] - m2), e1 = expf(hopw[1] - m2);
    sm[32] = e0 / (e0 + e1);
    sm[33] = e1 / (e0 + e1);
  }
}

__global__ void k_wbar(const float* __restrict__ Wh_w, const float* __restrict__ Wh_b, int H,
                       float* __restrict__ Wbar, float* __restrict__ bbar) {
  int j = blockIdx.x * 256 + threadIdx.x;
  float s = 0.f;
  for (int h = 0; h < H; ++h) s += Wh_w[h * 65536 + j];
  Wbar[j] = s / (float)H;
  if (j < DFEAT) {
    float b = 0.f;
    for (int h = 0; h < H; ++h) b += Wh_b[h * DFEAT + j];
    bbar[j] = b / (float)H;
  }
}

__global__ void k_wcat(const float* __restrict__ Wp_w, const float* __restrict__ Wp_b,
                       const float* __restrict__ sm, float* __restrict__ Wcat,
                       float* __restrict__ bcat) {
  int j = blockIdx.x * 256 + threadIdx.x;
  Wcat[j] = sm[j >> 13] * Wp_w[j];
  if (j < DFEAT) bcat[j] = sm[j >> 5] * Wp_b[j];
}

__global__ void k_mm(const float* __restrict__ A, const float* __restrict__ B,
                     float* __restrict__ C) {
  int i = blockIdx.x, d = threadIdx.x;
  float c = 0.f;
#pragma unroll 8
  for (int k = 0; k < DFEAT; ++k) c = fmaf(A[i * DFEAT + k], B[k * DFEAT + d], c);
  C[i * DFEAT + d] = c;
}

__global__ void k_cvec(const float* __restrict__ Wcat, const float* __restrict__ W1,
                       const float* __restrict__ bbar, const float* __restrict__ sm,
                       float* __restrict__ c1s, float* __restrict__ c2s) {
  int i = threadIdx.x;
  float s1 = 0.f, s2 = 0.f;
  for (int k = 0; k < DFEAT; ++k) {
    float b = bbar[k];
    s1 = fmaf(Wcat[i * DFEAT + k], b, s1);
    s2 = fmaf(W1[i * DFEAT + k], b, s2);
  }
  float hw0 = sm[32], hw1 = sm[33];
  c1s[i] = (hw0 + hw1) * s1;
  c2s[i] = hw1 * s2;
}

// pack B for MFMA, lane-linear chunks:
// flat = t*1024 + c*64 + chunk, chunk = lane = lg*16 + lr
// content: hw_t * W_t[col = c*16+lr][(t&7)*32 + lg*8 + j], j=0..7
__global__ void k_bprep(const float* __restrict__ W1, const float* __restrict__ W2,
                        const float* __restrict__ sm, unsigned short* __restrict__ Bpk) {
  int flat = blockIdx.x * 256 + threadIdx.x;  // 0..16383
  int t = flat >> 10;
  int c = (flat >> 6) & 15;
  int chunk = flat & 63;
  int lr = chunk & 15;
  int lg = chunk >> 4;
  const float* W = (t < 8) ? W1 : W2;
  const float hw = (t < 8) ? sm[32] : sm[33];
  const float* p = W + (c * 16 + lr) * DFEAT + (t & 7) * 32 + lg * 8;
  unsigned short o[8];
#pragma unroll
  for (int j = 0; j < 8; ++j) o[j] = f2bf(hw * p[j]);
  ulonglong2* dstp = reinterpret_cast<ulonglong2*>(Bpk + (size_t)flat * 8);
  *dstp = *reinterpret_cast<ulonglong2*>(o);
}

// x fp32 -> bf16
__global__ void k_xbf(const float* __restrict__ x, unsigned short* __restrict__ xbf, int n4) {
  int i = blockIdx.x * blockDim.x + threadIdx.x;
  if (i < n4) {
    float4 v = reinterpret_cast<const float4*>(x)[i];
    ushort4 o;
    o.x = f2bf(v.x); o.y = f2bf(v.y); o.z = f2bf(v.z); o.w = f2bf(v.w);
    reinterpret_cast<ushort4*>(xbf)[i] = o;
  }
}

// ---------------- edge pass: one wave per node, deep gather ILP ----------------
// half-wave (32 lanes x 16B) covers one 512B row; CSR indices preloaded (64/lane-reg)
// and shfl-broadcast; 4 gathers in flight per half-wave per superiteration.
// ALL __shfl calls sit in wave-uniform control flow (lane-dependent work is
// predicated INSIDE) so shuffle source lanes are always active.
__device__ __forceinline__ void acc8(float* a, const uint4 q) {
  a[0] += bf2f((unsigned short)(q.x & 0xffff));
  a[1] += bf2f((unsigned short)(q.x >> 16));
  a[2] += bf2f((unsigned short)(q.y & 0xffff));
  a[3] += bf2f((unsigned short)(q.y >> 16));
  a[4] += bf2f((unsigned short)(q.z & 0xffff));
  a[5] += bf2f((unsigned short)(q.z >> 16));
  a[6] += bf2f((unsigned short)(q.w & 0xffff));
  a[7] += bf2f((unsigned short)(q.w >> 16));
}

template <bool DOF>
__global__ void k_aggb3(const unsigned short* __restrict__ xbf, const int* __restrict__ csr,
                        const int* __restrict__ offs, const float* __restrict__ invd,
                        int N, unsigned short* __restrict__ outbf,
                        const float* __restrict__ mask, float* __restrict__ f) {
  const int wid = (blockIdx.x * blockDim.x + threadIdx.x) >> 6;
  const int lane = threadIdx.x & 63;
  if (wid >= N) return;
  const int half = lane >> 5, l5 = lane & 31;
  const int beg = offs[wid];
  const int cnt = offs[wid + 1] - beg;
  float a[8] = {0.f, 0.f, 0.f, 0.f, 0.f, 0.f, 0.f, 0.f};
  float fm = 0.f;

  for (int base = 0; base < cnt; base += 64) {   // uniform (cnt uniform per wave)
    const int m = min(64, cnt - base);
    int idx = 0;
    if (base + lane < cnt) idx = csr[beg + base + lane];
    int be = 0;
    // 8 edges per superiter (uniform loop): 4 independent gathers per half-wave
    for (; be + 8 <= m; be += 8) {
      const int s0 = __shfl(idx, be + half);
      const int s1 = __shfl(idx, be + 2 + half);
      const int s2 = __shfl(idx, be + 4 + half);
      const int s3 = __shfl(idx, be + 6 + half);
      const uint4 q0 = *reinterpret_cast<const uint4*>(xbf + (size_t)s0 * DFEAT + l5 * 8);
      const uint4 q1 = *reinterpret_cast<const uint4*>(xbf + (size_t)s1 * DFEAT + l5 * 8);
      const uint4 q2 = *reinterpret_cast<const uint4*>(xbf + (size_t)s2 * DFEAT + l5 * 8);
      const uint4 q3 = *reinterpret_cast<const uint4*>(xbf + (size_t)s3 * DFEAT + l5 * 8);
      acc8(a, q0); acc8(a, q1); acc8(a, q2); acc8(a, q3);
      if (DOF) fm += mask[s0] + mask[s1] + mask[s2] + mask[s3];
    }
    // tail: UNIFORM loop bound; shfl executed by all lanes with clamped (active)
    // source; per-lane work predicated inside. (Divergent-shfl fix.)
    for (int e0 = be; e0 < m; e0 += 2) {
      const int e = e0 + half;
      const int s = __shfl(idx, (e < m) ? e : 0);
      if (e < m) {
        const uint4 q = *reinterpret_cast<const uint4*>(xbf + (size_t)s * DFEAT + l5 * 8);
        acc8(a, q);
        if (DOF) fm += mask[s];
      }
    }
  }
#pragma unroll
  for (int j = 0; j < 8; ++j) a[j] += __shfl_xor(a[j], 32);
  const float w = invd[wid];
  if (lane < 32) {
    uint4 r;
    r.x = (unsigned)f2bf(a[0] * w) | ((unsigned)f2bf(a[1] * w) << 16);
    r.y = (unsigned)f2bf(a[2] * w) | ((unsigned)f2bf(a[3] * w) << 16);
    r.z = (unsigned)f2bf(a[4] * w) | ((unsigned)f2bf(a[5] * w) << 16);
    r.w = (unsigned)f2bf(a[6] * w) | ((unsigned)f2bf(a[7] * w) << 16);
    *reinterpret_cast<uint4*>(outbf + (size_t)wid * DFEAT + l5 * 8) = r;
  }
  if (DOF) {
    fm += __shfl_xor(fm, 32);
    if (lane == 0) f[wid] = fm * w;
  }
}

// ---------------- final GEMM via MFMA bf16, LDS-staged B + A/B register prefetch ----
// block = 256 thr = 4 waves, 64 rows x 256 cols; wave (rg,cg): rows rg*32..+31, cols cg*128..+127.
// B t-slice (16KB) double-buffered in LDS; A fragments for t+1 prefetched to regs before
// the barrier so post-barrier work is pure LDS+MFMA (global latency fully overlapped).
__global__ __launch_bounds__(256) void k_final_mfma(
    const unsigned short* __restrict__ m0bf, const unsigned short* __restrict__ mm0bf,
    const unsigned short* __restrict__ Bpk,
    const float* __restrict__ mask, const float* __restrict__ fbuf,
    const float* __restrict__ c1s, const float* __restrict__ c2s,
    const float* __restrict__ bcat, float* __restrict__ out, int N) {
  __shared__ uint4 Bs[2][1024];  // 2 x 16 KB
  const int tid = threadIdx.x;
  const int lane = tid & 63;
  const int wave = tid >> 6;
  const int lr = lane & 15;
  const int lg = lane >> 4;
  const int cg = wave & 1;   // col half (128 cols)
  const int rg = wave >> 1;  // row half (32 rows)
  const int r0 = blockIdx.x * 64 + rg * 32;
  const uint4* Bv = reinterpret_cast<const uint4*>(Bpk);

  f32x4 acc[2][8];
#pragma unroll
  for (int fr = 0; fr < 2; ++fr)
#pragma unroll
    for (int c = 0; c < 8; ++c) acc[fr][c] = (f32x4){0.f, 0.f, 0.f, 0.f};

  const int arow0 = r0 + lr;
  const int arow1 = r0 + 16 + lr;
  const bool ok0 = arow0 < N, ok1 = arow1 < N;
  const bf16x8 zf = (bf16x8){0, 0, 0, 0, 0, 0, 0, 0};

  uint4 g[4];
#pragma unroll
  for (int i = 0; i < 4; ++i) g[i] = Bv[i * 256 + tid];  // B slice t=0
  bf16x8 afn0 = zf, afn1 = zf;
  {
    const int kb = lg * 8;  // t=0
    if (ok0) afn0 = *reinterpret_cast<const bf16x8*>(m0bf + (size_t)arow0 * DFEAT + kb);
    if (ok1) afn1 = *reinterpret_cast<const bf16x8*>(m0bf + (size_t)arow1 * DFEAT + kb);
  }

  for (int t = 0; t < 16; ++t) {
    const int b = t & 1;
#pragma unroll
    for (int i = 0; i < 4; ++i) Bs[b][i * 256 + tid] = g[i];
    const bf16x8 af0 = afn0, af1 = afn1;
    if (t < 15) {
#pragma unroll
      for (int i = 0; i < 4; ++i) g[i] = Bv[(t + 1) * 1024 + i * 256 + tid];
      const unsigned short* As = (t + 1 < 8) ? m0bf : mm0bf;
      const int kb = ((t + 1) & 7) * 32 + lg * 8;
      afn0 = ok0 ? *reinterpret_cast<const bf16x8*>(As + (size_t)arow0 * DFEAT + kb) : zf;
      afn1 = ok1 ? *reinterpret_cast<const bf16x8*>(As + (size_t)arow1 * DFEAT + kb) : zf;
    }
    __syncthreads();
#pragma unroll
    for (int c = 0; c < 8; ++c) {
      const int ca = cg * 8 + c;
      const bf16x8 bf = *reinterpret_cast<const bf16x8*>(&Bs[b][ca * 64 + lane]);
      acc[0][c] = __builtin_amdgcn_mfma_f32_16x16x32_bf16(af0, bf, acc[0][c], 0, 0, 0);
      acc[1][c] = __builtin_amdgcn_mfma_f32_16x16x32_bf16(af1, bf, acc[1][c], 0, 0, 0);
    }
    // dbuf: writes at t+2 target this buffer only after barrier(t+1) -> safe
  }

  // epilogue: row = r0 + fr*16 + lg*4 + i, col = cg*128 + c*16 + lr
  float c1v[8], c2v[8], bcv[8];
#pragma unroll
  for (int c = 0; c < 8; ++c) {
    const int col = cg * 128 + c * 16 + lr;
    c1v[c] = c1s[col]; c2v[c] = c2s[col]; bcv[c] = bcat[col];
  }
#pragma unroll
  for (int fr = 0; fr < 2; ++fr) {
#pragma unroll
    for (int i = 0; i < 4; ++i) {
      const int r = r0 + fr * 16 + lg * 4 + i;
      if (r < N) {
        const float mk = mask[r];
        const float fv = fbuf[r];
        float* orow = out + (size_t)r * DFEAT + cg * 128 + lr;
#pragma unroll
        for (int c = 0; c < 8; ++c)
          orow[c * 16] = acc[fr][c][i] + mk * c1v[c] + fv * c2v[c] + bcv[c];
      }
    }
  }
}

// ---------------- host ----------------
extern "C" void kernel_launch(void* const* d_in, const int* in_sizes, int n_in,
                              void* d_out, int out_size, void* d_ws, size_t ws_size,
                              hipStream_t stream) {
  const float* x    = (const float*)d_in[0];
  const float* Wh_w = (const float*)d_in[1];
  const float* Wh_b = (const float*)d_in[2];
  const float* Wp_w = (const float*)d_in[3];
  const float* Wp_b = (const float*)d_in[4];
  const float* gate = (const float*)d_in[5];
  const float* hopw = (const float*)d_in[6];
  const int* src    = (const int*)d_in[7];
  const int* dst    = (const int*)d_in[8];

  const int H = in_sizes[5];
  const int E = in_sizes[7];
  const int N = in_sizes[0] / DFEAT;
  float* out = (float*)d_out;

  char* w = (char*)d_ws;
  auto take = [&](size_t bytes) -> char* {
    char* p = w;
    w += (bytes + 255) & ~(size_t)255;
    return p;
  };
  unsigned short* xbf   = (unsigned short*)take((size_t)N * DFEAT * 2);
  unsigned short* m0bf  = (unsigned short*)take((size_t)N * DFEAT * 2);
  unsigned short* mm0bf = (unsigned short*)take((size_t)N * DFEAT * 2);
  unsigned short* Bpk   = (unsigned short*)take((size_t)512 * 256 * 2);
  int* csr     = (int*)take((size_t)E * 4);
  int* offs    = (int*)take((size_t)(N + 1) * 4);
  int* cursor  = (int*)take((size_t)N * 4);
  int* deg     = (int*)take((size_t)N * 4);
  float* invd  = (float*)take((size_t)N * 4);
  float* mask  = (float*)take((size_t)N * 4);
  float* fbuf  = (float*)take((size_t)N * 4);
  float* Wbar  = (float*)take(65536 * 4);
  float* Wcat  = (float*)take(65536 * 4);
  float* W1    = (float*)take(65536 * 4);
  float* W2    = (float*)take(65536 * 4);
  float* bbar  = (float*)take(256 * 4);
  float* bcat  = (float*)take(256 * 4);
  float* c1s   = (float*)take(256 * 4);
  float* c2s   = (float*)take(256 * 4);
  float* sm    = (float*)take(64 * 4);
  int* bsum    = (int*)take(256 * 4);

  const int nScanBlocks = (N + 255) / 256;

  // graph structure
  hipMemsetAsync(deg, 0, (size_t)N * 4, stream);
  k_deg<<<(E + 255) / 256, 256, 0, stream>>>(dst, E, deg);
  k_scan1<<<nScanBlocks, 256, 0, stream>>>(deg, N, bsum);
  k_scan2<<<1, 256, 0, stream>>>(bsum, nScanBlocks);
  k_scan3<<<nScanBlocks, 256, 0, stream>>>(deg, bsum, N, offs, cursor, invd, mask);
  k_fill<<<(E + 255) / 256, 256, 0, stream>>>(src, dst, E, cursor, csr);

  // x -> bf16
  k_xbf<<<(N * DFEAT / 4 + 255) / 256, 256, 0, stream>>>(x, xbf, N * DFEAT / 4);

  // folded weights
  k_softmax<<<1, 64, 0, stream>>>(gate, H, hopw, sm);
  k_wbar<<<256, 256, 0, stream>>>(Wh_w, Wh_b, H, Wbar, bbar);
  k_wcat<<<256, 256, 0, stream>>>(Wp_w, Wp_b, sm, Wcat, bcat);
  k_mm<<<256, 256, 0, stream>>>(Wcat, Wbar, W1);
  k_mm<<<256, 256, 0, stream>>>(W1, Wbar, W2);
  k_cvec<<<1, 256, 0, stream>>>(Wcat, W1, bbar, sm, c1s, c2s);
  k_bprep<<<64, 256, 0, stream>>>(W1, W2, sm, Bpk);

  // m0bf = meanagg(xbf) ; mm0bf = meanagg(m0bf) (+ f = meanagg(mask))
  const int aggBlocks = (N + 3) / 4;
  k_aggb3<false><<<aggBlocks, 256, 0, stream>>>(xbf, csr, offs, invd, N, m0bf, nullptr, nullptr);
  k_aggb3<true><<<aggBlocks, 256, 0, stream>>>(m0bf, csr, offs, invd, N, mm0bf, mask, fbuf);

  // out = [m0|mm0] @ Bpk + mask*c1s + f*c2s + bcat
  k_final_mfma<<<(N + 63) / 64, 256, 0, stream>>>(m0bf, mm0bf, Bpk, mask, fbuf,
                                                  c1s, c2s, bcat, out, N);
}

// Round 7
// 323.829 us; speedup vs baseline: 1.9437x; 1.0988x over previous
//
#include <hip/hip_runtime.h>
#include <math.h>

#define DFEAT 256

typedef short bf16x8 __attribute__((ext_vector_type(8)));
typedef float f32x4 __attribute__((ext_vector_type(4)));

__device__ __forceinline__ unsigned short f2bf(float f) {
  union { float f; unsigned int u; } v;
  v.f = f;
  unsigned int r = v.u + 0x7fff + ((v.u >> 16) & 1);  // RNE
  return (unsigned short)(r >> 16);
}
__device__ __forceinline__ float bf2f(unsigned short b) {
  union { float f; unsigned int u; } v;
  v.u = ((unsigned int)b) << 16;
  return v.f;
}

// ---------------- graph setup ----------------
__global__ void k_deg(const int* __restrict__ dst, int E, int* __restrict__ deg) {
  int i = blockIdx.x * blockDim.x + threadIdx.x;
  if (i < E) atomicAdd(&deg[dst[i]], 1);
}

// ---------------- parallel 3-phase exclusive scan ----------------
__device__ __forceinline__ int wave_incl_scan(int x, int lane) {
#pragma unroll
  for (int off = 1; off < 64; off <<= 1) {
    int t = __shfl_up(x, off);
    if (lane >= off) x += t;
  }
  return x;
}

__global__ void k_scan1(const int* __restrict__ deg, int N, int* __restrict__ bsum) {
  const int tid = threadIdx.x, lane = tid & 63, wave = tid >> 6;
  int i = blockIdx.x * 256 + tid;
  int v = (i < N) ? deg[i] : 0;
  int s = v;
#pragma unroll
  for (int off = 1; off < 64; off <<= 1) s += __shfl_xor(s, off);
  __shared__ int ws[4];
  if (lane == 0) ws[wave] = s;
  __syncthreads();
  if (tid == 0) bsum[blockIdx.x] = ws[0] + ws[1] + ws[2] + ws[3];
}

__global__ void k_scan2(int* __restrict__ bsum, int nb) {
  const int tid = threadIdx.x, lane = tid & 63, wave = tid >> 6;
  int v = (tid < nb) ? bsum[tid] : 0;
  int incl = wave_incl_scan(v, lane);
  __shared__ int ws[4];
  if (lane == 63) ws[wave] = incl;
  __syncthreads();
  int add = 0;
  for (int w = 0; w < wave; ++w) add += ws[w];
  if (tid < nb) bsum[tid] = add + incl - v;  // exclusive
}

// scan3 + invdeg/mask fused
__global__ void k_scan3(const int* __restrict__ deg, const int* __restrict__ bexcl, int N,
                        int* __restrict__ offs, int* __restrict__ cursor,
                        float* __restrict__ invd, float* __restrict__ mask) {
  const int tid = threadIdx.x, lane = tid & 63, wave = tid >> 6;
  int i = blockIdx.x * 256 + tid;
  int v = (i < N) ? deg[i] : 0;
  int incl = wave_incl_scan(v, lane);
  __shared__ int ws[4];
  if (lane == 63) ws[wave] = incl;
  __syncthreads();
  int add = bexcl[blockIdx.x];
  for (int w = 0; w < wave; ++w) add += ws[w];
  if (i < N) {
    offs[i + 1] = add + incl;
    cursor[i] = add + incl - v;
    invd[i] = v > 0 ? 1.0f / (float)v : 0.0f;
    mask[i] = v > 0 ? 1.0f : 0.0f;
  }
  if (i == 0) offs[0] = 0;
}

__global__ void k_fill(const int* __restrict__ src, const int* __restrict__ dst, int E,
                       int* __restrict__ cursor, int* __restrict__ csr) {
  int i = blockIdx.x * blockDim.x + threadIdx.x;
  if (i < E) {
    int p = atomicAdd(&cursor[dst[i]], 1);
    csr[p] = src[i];
  }
}

// ---------------- weight precompute ----------------
__global__ void k_softmax(const float* __restrict__ gate, int H,
                          const float* __restrict__ hopw, float* __restrict__ sm) {
  if (blockIdx.x == 0 && threadIdx.x == 0) {
    float mx = -1e30f;
    for (int h = 0; h < H; ++h) mx = fmaxf(mx, gate[h]);
    float s = 0.f;
    for (int h = 0; h < H; ++h) { float e = expf(gate[h] - mx); sm[h] = e; s += e; }
    for (int h = 0; h < H; ++h) sm[h] /= s;
    float m2 = fmaxf(hopw[0], hopw[1]);
    float e0 = expf(hopw[0] - m2), e1 = expf(hopw[1] - m2);
    sm[32] = e0 / (e0 + e1);
    sm[33] = e1 / (e0 + e1);
  }
}

__global__ void k_wbar(const float* __restrict__ Wh_w, const float* __restrict__ Wh_b, int H,
                       float* __restrict__ Wbar, float* __restrict__ bbar) {
  int j = blockIdx.x * 256 + threadIdx.x;
  float s = 0.f;
  for (int h = 0; h < H; ++h) s += Wh_w[h * 65536 + j];
  Wbar[j] = s / (float)H;
  if (j < DFEAT) {
    float b = 0.f;
    for (int h = 0; h < H; ++h) b += Wh_b[h * DFEAT + j];
    bbar[j] = b / (float)H;
  }
}

__global__ void k_wcat(const float* __restrict__ Wp_w, const float* __restrict__ Wp_b,
                       const float* __restrict__ sm, float* __restrict__ Wcat,
                       float* __restrict__ bcat) {
  int j = blockIdx.x * 256 + threadIdx.x;
  Wcat[j] = sm[j >> 13] * Wp_w[j];
  if (j < DFEAT) bcat[j] = sm[j >> 5] * Wp_b[j];
}

__global__ void k_mm(const float* __restrict__ A, const float* __restrict__ B,
                     float* __restrict__ C) {
  int i = blockIdx.x, d = threadIdx.x;
  float c = 0.f;
#pragma unroll 8
  for (int k = 0; k < DFEAT; ++k) c = fmaf(A[i * DFEAT + k], B[k * DFEAT + d], c);
  C[i * DFEAT + d] = c;
}

__global__ void k_cvec(const float* __restrict__ Wcat, const float* __restrict__ W1,
                       const float* __restrict__ bbar, const float* __restrict__ sm,
                       float* __restrict__ c1s, float* __restrict__ c2s) {
  int i = threadIdx.x;
  float s1 = 0.f, s2 = 0.f;
  for (int k = 0; k < DFEAT; ++k) {
    float b = bbar[k];
    s1 = fmaf(Wcat[i * DFEAT + k], b, s1);
    s2 = fmaf(W1[i * DFEAT + k], b, s2);
  }
  float hw0 = sm[32], hw1 = sm[33];
  c1s[i] = (hw0 + hw1) * s1;
  c2s[i] = hw1 * s2;
}

// pack B for MFMA, lane-linear chunks:
// flat = t*1024 + c*64 + chunk, chunk = lane = lg*16 + lr
// content: hw_t * W_t[col = c*16+lr][(t&7)*32 + lg*8 + j], j=0..7
__global__ void k_bprep(const float* __restrict__ W1, const float* __restrict__ W2,
                        const float* __restrict__ sm, unsigned short* __restrict__ Bpk) {
  int flat = blockIdx.x * 256 + threadIdx.x;  // 0..16383
  int t = flat >> 10;
  int c = (flat >> 6) & 15;
  int chunk = flat & 63;
  int lr = chunk & 15;
  int lg = chunk >> 4;
  const float* W = (t < 8) ? W1 : W2;
  const float hw = (t < 8) ? sm[32] : sm[33];
  const float* p = W + (c * 16 + lr) * DFEAT + (t & 7) * 32 + lg * 8;
  unsigned short o[8];
#pragma unroll
  for (int j = 0; j < 8; ++j) o[j] = f2bf(hw * p[j]);
  ulonglong2* dstp = reinterpret_cast<ulonglong2*>(Bpk + (size_t)flat * 8);
  *dstp = *reinterpret_cast<ulonglong2*>(o);
}

// x fp32 -> bf16
__global__ void k_xbf(const float* __restrict__ x, unsigned short* __restrict__ xbf, int n4) {
  int i = blockIdx.x * blockDim.x + threadIdx.x;
  if (i < n4) {
    float4 v = reinterpret_cast<const float4*>(x)[i];
    ushort4 o;
    o.x = f2bf(v.x); o.y = f2bf(v.y); o.z = f2bf(v.z); o.w = f2bf(v.w);
    reinterpret_cast<ushort4*>(xbf)[i] = o;
  }
}

// ---------------- edge pass: one wave per node, deep gather ILP ----------------
__device__ __forceinline__ void acc8(float* a, const uint4 q) {
  a[0] += bf2f((unsigned short)(q.x & 0xffff));
  a[1] += bf2f((unsigned short)(q.x >> 16));
  a[2] += bf2f((unsigned short)(q.y & 0xffff));
  a[3] += bf2f((unsigned short)(q.y >> 16));
  a[4] += bf2f((unsigned short)(q.z & 0xffff));
  a[5] += bf2f((unsigned short)(q.z >> 16));
  a[6] += bf2f((unsigned short)(q.w & 0xffff));
  a[7] += bf2f((unsigned short)(q.w >> 16));
}

template <bool DOF>
__global__ void k_aggb3(const unsigned short* __restrict__ xbf, const int* __restrict__ csr,
                        const int* __restrict__ offs, const float* __restrict__ invd,
                        int N, unsigned short* __restrict__ outbf,
                        const float* __restrict__ mask, float* __restrict__ f) {
  const int wid = (blockIdx.x * blockDim.x + threadIdx.x) >> 6;
  const int lane = threadIdx.x & 63;
  if (wid >= N) return;
  const int half = lane >> 5, l5 = lane & 31;
  const int beg = offs[wid];
  const int cnt = offs[wid + 1] - beg;
  float a[8] = {0.f, 0.f, 0.f, 0.f, 0.f, 0.f, 0.f, 0.f};
  float fm = 0.f;

  for (int base = 0; base < cnt; base += 64) {   // uniform (cnt uniform per wave)
    const int m = min(64, cnt - base);
    int idx = 0;
    if (base + lane < cnt) idx = csr[beg + base + lane];
    int be = 0;
    for (; be + 8 <= m; be += 8) {
      const int s0 = __shfl(idx, be + half);
      const int s1 = __shfl(idx, be + 2 + half);
      const int s2 = __shfl(idx, be + 4 + half);
      const int s3 = __shfl(idx, be + 6 + half);
      const uint4 q0 = *reinterpret_cast<const uint4*>(xbf + (size_t)s0 * DFEAT + l5 * 8);
      const uint4 q1 = *reinterpret_cast<const uint4*>(xbf + (size_t)s1 * DFEAT + l5 * 8);
      const uint4 q2 = *reinterpret_cast<const uint4*>(xbf + (size_t)s2 * DFEAT + l5 * 8);
      const uint4 q3 = *reinterpret_cast<const uint4*>(xbf + (size_t)s3 * DFEAT + l5 * 8);
      acc8(a, q0); acc8(a, q1); acc8(a, q2); acc8(a, q3);
      if (DOF) fm += mask[s0] + mask[s1] + mask[s2] + mask[s3];
    }
    // tail: uniform loop bound; shfl with clamped (active) source; work predicated.
    for (int e0 = be; e0 < m; e0 += 2) {
      const int e = e0 + half;
      const int s = __shfl(idx, (e < m) ? e : 0);
      if (e < m) {
        const uint4 q = *reinterpret_cast<const uint4*>(xbf + (size_t)s * DFEAT + l5 * 8);
        acc8(a, q);
        if (DOF) fm += mask[s];
      }
    }
  }
#pragma unroll
  for (int j = 0; j < 8; ++j) a[j] += __shfl_xor(a[j], 32);
  const float w = invd[wid];
  if (lane < 32) {
    uint4 r;
    r.x = (unsigned)f2bf(a[0] * w) | ((unsigned)f2bf(a[1] * w) << 16);
    r.y = (unsigned)f2bf(a[2] * w) | ((unsigned)f2bf(a[3] * w) << 16);
    r.z = (unsigned)f2bf(a[4] * w) | ((unsigned)f2bf(a[5] * w) << 16);
    r.w = (unsigned)f2bf(a[6] * w) | ((unsigned)f2bf(a[7] * w) << 16);
    *reinterpret_cast<uint4*>(outbf + (size_t)wid * DFEAT + l5 * 8) = r;
  }
  if (DOF) {
    fm += __shfl_xor(fm, 32);
    if (lane == 0) f[wid] = fm * w;
  }
}

// ---------------- final GEMM via MFMA bf16: barrier-free, B in registers ----------
// Each wave independently owns 16 rows x 256 cols. Per K-slice t: load ALL 16
// B-fragments into regs (16 KB in flight) + prefetch next A-frag, then 16 MFMAs.
// No LDS, no __syncthreads -> no vmcnt(0) drain; deep MLP hides L2/L3 latency.
__global__ __launch_bounds__(256) void k_final_mfma(
    const unsigned short* __restrict__ m0bf, const unsigned short* __restrict__ mm0bf,
    const unsigned short* __restrict__ Bpk,
    const float* __restrict__ mask, const float* __restrict__ fbuf,
    const float* __restrict__ c1s, const float* __restrict__ c2s,
    const float* __restrict__ bcat, float* __restrict__ out, int N) {
  const int tid = threadIdx.x;
  const int lane = tid & 63;
  const int wave = tid >> 6;
  const int r0 = blockIdx.x * 64 + wave * 16;
  if (r0 >= N) return;  // wave-uniform; no barriers in kernel
  const int lr = lane & 15;  // A-row / D-col within tile
  const int lg = lane >> 4;  // k-group
  const uint4* Bv = reinterpret_cast<const uint4*>(Bpk);

  f32x4 acc[16];
#pragma unroll
  for (int c = 0; c < 16; ++c) acc[c] = (f32x4){0.f, 0.f, 0.f, 0.f};

  const int arow = r0 + lr;
  const bool okA = arow < N;
  const size_t abase = (size_t)arow * DFEAT + lg * 8;
  const bf16x8 zf = (bf16x8){0, 0, 0, 0, 0, 0, 0, 0};

  bf16x8 an = okA ? *reinterpret_cast<const bf16x8*>(m0bf + abase) : zf;  // t=0

  for (int t = 0; t < 16; ++t) {
    // issue all 16 B-fragment loads (coalesced 1KB/wave each, independent)
    bf16x8 b[16];
#pragma unroll
    for (int c = 0; c < 16; ++c)
      b[c] = *reinterpret_cast<const bf16x8*>(&Bv[t * 1024 + c * 64 + lane]);
    const bf16x8 a = an;
    if (t < 15) {  // prefetch next A-fragment
      const unsigned short* As = (t + 1 < 8) ? m0bf : mm0bf;
      an = okA ? *reinterpret_cast<const bf16x8*>(As + abase + ((t + 1) & 7) * 32) : zf;
    }
#pragma unroll
    for (int c = 0; c < 16; ++c)
      acc[c] = __builtin_amdgcn_mfma_f32_16x16x32_bf16(a, b[c], acc[c], 0, 0, 0);
  }

  // epilogue: lane covers rows rbase..rbase+3, col = c*16+lr
  const int rbase = r0 + lg * 4;
  float mk[4], fv[4];
#pragma unroll
  for (int i = 0; i < 4; ++i) {
    int r = rbase + i;
    mk[i] = (r < N) ? mask[r] : 0.f;
    fv[i] = (r < N) ? fbuf[r] : 0.f;
  }
#pragma unroll
  for (int c = 0; c < 16; ++c) {
    const int col = c * 16 + lr;
    const float c1 = c1s[col], c2 = c2s[col], bc = bcat[col];
#pragma unroll
    for (int i = 0; i < 4; ++i) {
      const int r = rbase + i;
      if (r < N) out[(size_t)r * DFEAT + col] = acc[c][i] + mk[i] * c1 + fv[i] * c2 + bc;
    }
  }
}

// ---------------- host ----------------
extern "C" void kernel_launch(void* const* d_in, const int* in_sizes, int n_in,
                              void* d_out, int out_size, void* d_ws, size_t ws_size,
                              hipStream_t stream) {
  const float* x    = (const float*)d_in[0];
  const float* Wh_w = (const float*)d_in[1];
  const float* Wh_b = (const float*)d_in[2];
  const float* Wp_w = (const float*)d_in[3];
  const float* Wp_b = (const float*)d_in[4];
  const float* gate = (const float*)d_in[5];
  const float* hopw = (const float*)d_in[6];
  const int* src    = (const int*)d_in[7];
  const int* dst    = (const int*)d_in[8];

  const int H = in_sizes[5];
  const int E = in_sizes[7];
  const int N = in_sizes[0] / DFEAT;
  float* out = (float*)d_out;

  char* w = (char*)d_ws;
  auto take = [&](size_t bytes) -> char* {
    char* p = w;
    w += (bytes + 255) & ~(size_t)255;
    return p;
  };
  unsigned short* xbf   = (unsigned short*)take((size_t)N * DFEAT * 2);
  unsigned short* m0bf  = (unsigned short*)take((size_t)N * DFEAT * 2);
  unsigned short* mm0bf = (unsigned short*)take((size_t)N * DFEAT * 2);
  unsigned short* Bpk   = (unsigned short*)take((size_t)512 * 256 * 2);
  int* csr     = (int*)take((size_t)E * 4);
  int* offs    = (int*)take((size_t)(N + 1) * 4);
  int* cursor  = (int*)take((size_t)N * 4);
  int* deg     = (int*)take((size_t)N * 4);
  float* invd  = (float*)take((size_t)N * 4);
  float* mask  = (float*)take((size_t)N * 4);
  float* fbuf  = (float*)take((size_t)N * 4);
  float* Wbar  = (float*)take(65536 * 4);
  float* Wcat  = (float*)take(65536 * 4);
  float* W1    = (float*)take(65536 * 4);
  float* W2    = (float*)take(65536 * 4);
  float* bbar  = (float*)take(256 * 4);
  float* bcat  = (float*)take(256 * 4);
  float* c1s   = (float*)take(256 * 4);
  float* c2s   = (float*)take(256 * 4);
  float* sm    = (float*)take(64 * 4);
  int* bsum    = (int*)take(256 * 4);

  const int nScanBlocks = (N + 255) / 256;

  // graph structure
  hipMemsetAsync(deg, 0, (size_t)N * 4, stream);
  k_deg<<<(E + 255) / 256, 256, 0, stream>>>(dst, E, deg);
  k_scan1<<<nScanBlocks, 256, 0, stream>>>(deg, N, bsum);
  k_scan2<<<1, 256, 0, stream>>>(bsum, nScanBlocks);
  k_scan3<<<nScanBlocks, 256, 0, stream>>>(deg, bsum, N, offs, cursor, invd, mask);
  k_fill<<<(E + 255) / 256, 256, 0, stream>>>(src, dst, E, cursor, csr);

  // x -> bf16
  k_xbf<<<(N * DFEAT / 4 + 255) / 256, 256, 0, stream>>>(x, xbf, N * DFEAT / 4);

  // folded weights
  k_softmax<<<1, 64, 0, stream>>>(gate, H, hopw, sm);
  k_wbar<<<256, 256, 0, stream>>>(Wh_w, Wh_b, H, Wbar, bbar);
  k_wcat<<<256, 256, 0, stream>>>(Wp_w, Wp_b, sm, Wcat, bcat);
  k_mm<<<256, 256, 0, stream>>>(Wcat, Wbar, W1);
  k_mm<<<256, 256, 0, stream>>>(W1, Wbar, W2);
  k_cvec<<<1, 256, 0, stream>>>(Wcat, W1, bbar, sm, c1s, c2s);
  k_bprep<<<64, 256, 0, stream>>>(W1, W2, sm, Bpk);

  // m0bf = meanagg(xbf) ; mm0bf = meanagg(m0bf) (+ f = meanagg(mask))
  const int aggBlocks = (N + 3) / 4;
  k_aggb3<false><<<aggBlocks, 256, 0, stream>>>(xbf, csr, offs, invd, N, m0bf, nullptr, nullptr);
  k_aggb3<true><<<aggBlocks, 256, 0, stream>>>(m0bf, csr, offs, invd, N, mm0bf, mask, fbuf);

  // out = [m0|mm0] @ Bpk + mask*c1s + f*c2s + bcat
  k_final_mfma<<<(N + 63) / 64, 256, 0, stream>>>(m0bf, mm0bf, Bpk, mask, fbuf,
                                                  c1s, c2s, bcat, out, N);
}

// Round 8
// 316.404 us; speedup vs baseline: 1.9893x; 1.0235x over previous
//
#include <hip/hip_runtime.h>
#include <math.h>

#define DFEAT 256

typedef short bf16x8 __attribute__((ext_vector_type(8)));
typedef float f32x4 __attribute__((ext_vector_type(4)));

__device__ __forceinline__ unsigned short f2bf(float f) {
  union { float f; unsigned int u; } v;
  v.f = f;
  unsigned int r = v.u + 0x7fff + ((v.u >> 16) & 1);  // RNE
  return (unsigned short)(r >> 16);
}
__device__ __forceinline__ float bf2f(unsigned short b) {
  union { float f; unsigned int u; } v;
  v.u = ((unsigned int)b) << 16;
  return v.f;
}

// ---------------- graph setup ----------------
__global__ void k_deg(const int* __restrict__ dst, int E, int* __restrict__ deg) {
  int i = blockIdx.x * blockDim.x + threadIdx.x;
  if (i < E) atomicAdd(&deg[dst[i]], 1);
}

// ---------------- parallel 3-phase exclusive scan ----------------
__device__ __forceinline__ int wave_incl_scan(int x, int lane) {
#pragma unroll
  for (int off = 1; off < 64; off <<= 1) {
    int t = __shfl_up(x, off);
    if (lane >= off) x += t;
  }
  return x;
}

__global__ void k_scan1(const int* __restrict__ deg, int N, int* __restrict__ bsum) {
  const int tid = threadIdx.x, lane = tid & 63, wave = tid >> 6;
  int i = blockIdx.x * 256 + tid;
  int v = (i < N) ? deg[i] : 0;
  int s = v;
#pragma unroll
  for (int off = 1; off < 64; off <<= 1) s += __shfl_xor(s, off);
  __shared__ int ws[4];
  if (lane == 0) ws[wave] = s;
  __syncthreads();
  if (tid == 0) bsum[blockIdx.x] = ws[0] + ws[1] + ws[2] + ws[3];
}

__global__ void k_scan2(int* __restrict__ bsum, int nb) {
  const int tid = threadIdx.x, lane = tid & 63, wave = tid >> 6;
  int v = (tid < nb) ? bsum[tid] : 0;
  int incl = wave_incl_scan(v, lane);
  __shared__ int ws[4];
  if (lane == 63) ws[wave] = incl;
  __syncthreads();
  int add = 0;
  for (int w = 0; w < wave; ++w) add += ws[w];
  if (tid < nb) bsum[tid] = add + incl - v;  // exclusive
}

// scan3 + invdeg/mask fused
__global__ void k_scan3(const int* __restrict__ deg, const int* __restrict__ bexcl, int N,
                        int* __restrict__ offs, int* __restrict__ cursor,
                        float* __restrict__ invd, float* __restrict__ mask) {
  const int tid = threadIdx.x, lane = tid & 63, wave = tid >> 6;
  int i = blockIdx.x * 256 + tid;
  int v = (i < N) ? deg[i] : 0;
  int incl = wave_incl_scan(v, lane);
  __shared__ int ws[4];
  if (lane == 63) ws[wave] = incl;
  __syncthreads();
  int add = bexcl[blockIdx.x];
  for (int w = 0; w < wave; ++w) add += ws[w];
  if (i < N) {
    offs[i + 1] = add + incl;
    cursor[i] = add + incl - v;
    invd[i] = v > 0 ? 1.0f / (float)v : 0.0f;
    mask[i] = v > 0 ? 1.0f : 0.0f;
  }
  if (i == 0) offs[0] = 0;
}

__global__ void k_fill(const int* __restrict__ src, const int* __restrict__ dst, int E,
                       int* __restrict__ cursor, int* __restrict__ csr) {
  int i = blockIdx.x * blockDim.x + threadIdx.x;
  if (i < E) {
    int p = atomicAdd(&cursor[dst[i]], 1);
    csr[p] = src[i];
  }
}

// ---------------- weight precompute ----------------
__global__ void k_softmax(const float* __restrict__ gate, int H,
                          const float* __restrict__ hopw, float* __restrict__ sm) {
  if (blockIdx.x == 0 && threadIdx.x == 0) {
    float mx = -1e30f;
    for (int h = 0; h < H; ++h) mx = fmaxf(mx, gate[h]);
    float s = 0.f;
    for (int h = 0; h < H; ++h) { float e = expf(gate[h] - mx); sm[h] = e; s += e; }
    for (int h = 0; h < H; ++h) sm[h] /= s;
    float m2 = fmaxf(hopw[0], hopw[1]);
    float e0 = expf(hopw[0] - m2), e1 = expf(hopw[1] - m2);
    sm[32] = e0 / (e0 + e1);
    sm[33] = e1 / (e0 + e1);
  }
}

__global__ void k_wbar(const float* __restrict__ Wh_w, const float* __restrict__ Wh_b, int H,
                       float* __restrict__ Wbar, float* __restrict__ bbar) {
  int j = blockIdx.x * 256 + threadIdx.x;
  float s = 0.f;
  for (int h = 0; h < H; ++h) s += Wh_w[h * 65536 + j];
  Wbar[j] = s / (float)H;
  if (j < DFEAT) {
    float b = 0.f;
    for (int h = 0; h < H; ++h) b += Wh_b[h * DFEAT + j];
    bbar[j] = b / (float)H;
  }
}

__global__ void k_wcat(const float* __restrict__ Wp_w, const float* __restrict__ Wp_b,
                       const float* __restrict__ sm, float* __restrict__ Wcat,
                       float* __restrict__ bcat) {
  int j = blockIdx.x * 256 + threadIdx.x;
  Wcat[j] = sm[j >> 13] * Wp_w[j];
  if (j < DFEAT) bcat[j] = sm[j >> 5] * Wp_b[j];
}

__global__ void k_mm(const float* __restrict__ A, const float* __restrict__ B,
                     float* __restrict__ C) {
  int i = blockIdx.x, d = threadIdx.x;
  float c = 0.f;
#pragma unroll 8
  for (int k = 0; k < DFEAT; ++k) c = fmaf(A[i * DFEAT + k], B[k * DFEAT + d], c);
  C[i * DFEAT + d] = c;
}

__global__ void k_cvec(const float* __restrict__ Wcat, const float* __restrict__ W1,
                       const float* __restrict__ bbar, const float* __restrict__ sm,
                       float* __restrict__ c1s, float* __restrict__ c2s) {
  int i = threadIdx.x;
  float s1 = 0.f, s2 = 0.f;
  for (int k = 0; k < DFEAT; ++k) {
    float b = bbar[k];
    s1 = fmaf(Wcat[i * DFEAT + k], b, s1);
    s2 = fmaf(W1[i * DFEAT + k], b, s2);
  }
  float hw0 = sm[32], hw1 = sm[33];
  c1s[i] = (hw0 + hw1) * s1;
  c2s[i] = hw1 * s2;
}

// pack B for MFMA, lane-linear chunks:
// flat = t*1024 + c*64 + chunk, chunk = lane = lg*16 + lr
// content: hw_t * W_t[col = c*16+lr][(t&7)*32 + lg*8 + j], j=0..7
__global__ void k_bprep(const float* __restrict__ W1, const float* __restrict__ W2,
                        const float* __restrict__ sm, unsigned short* __restrict__ Bpk) {
  int flat = blockIdx.x * 256 + threadIdx.x;  // 0..16383
  int t = flat >> 10;
  int c = (flat >> 6) & 15;
  int chunk = flat & 63;
  int lr = chunk & 15;
  int lg = chunk >> 4;
  const float* W = (t < 8) ? W1 : W2;
  const float hw = (t < 8) ? sm[32] : sm[33];
  const float* p = W + (c * 16 + lr) * DFEAT + (t & 7) * 32 + lg * 8;
  unsigned short o[8];
#pragma unroll
  for (int j = 0; j < 8; ++j) o[j] = f2bf(hw * p[j]);
  ulonglong2* dstp = reinterpret_cast<ulonglong2*>(Bpk + (size_t)flat * 8);
  *dstp = *reinterpret_cast<ulonglong2*>(o);
}

// x fp32 -> bf16
__global__ void k_xbf(const float* __restrict__ x, unsigned short* __restrict__ xbf, int n4) {
  int i = blockIdx.x * blockDim.x + threadIdx.x;
  if (i < n4) {
    float4 v = reinterpret_cast<const float4*>(x)[i];
    ushort4 o;
    o.x = f2bf(v.x); o.y = f2bf(v.y); o.z = f2bf(v.z); o.w = f2bf(v.w);
    reinterpret_cast<ushort4*>(xbf)[i] = o;
  }
}

// ---------------- edge pass: one wave per node, deep gather ILP ----------------
__device__ __forceinline__ void acc8(float* a, const uint4 q) {
  a[0] += bf2f((unsigned short)(q.x & 0xffff));
  a[1] += bf2f((unsigned short)(q.x >> 16));
  a[2] += bf2f((unsigned short)(q.y & 0xffff));
  a[3] += bf2f((unsigned short)(q.y >> 16));
  a[4] += bf2f((unsigned short)(q.z & 0xffff));
  a[5] += bf2f((unsigned short)(q.z >> 16));
  a[6] += bf2f((unsigned short)(q.w & 0xffff));
  a[7] += bf2f((unsigned short)(q.w >> 16));
}

template <bool DOF>
__global__ void k_aggb3(const unsigned short* __restrict__ xbf, const int* __restrict__ csr,
                        const int* __restrict__ offs, const float* __restrict__ invd,
                        int N, unsigned short* __restrict__ outbf,
                        const float* __restrict__ mask, float* __restrict__ f) {
  const int wid = (blockIdx.x * blockDim.x + threadIdx.x) >> 6;
  const int lane = threadIdx.x & 63;
  if (wid >= N) return;
  const int half = lane >> 5, l5 = lane & 31;
  const int beg = offs[wid];
  const int cnt = offs[wid + 1] - beg;
  float a[8] = {0.f, 0.f, 0.f, 0.f, 0.f, 0.f, 0.f, 0.f};
  float fm = 0.f;

  for (int base = 0; base < cnt; base += 64) {   // uniform (cnt uniform per wave)
    const int m = min(64, cnt - base);
    int idx = 0;
    if (base + lane < cnt) idx = csr[beg + base + lane];
    int be = 0;
    for (; be + 8 <= m; be += 8) {
      const int s0 = __shfl(idx, be + half);
      const int s1 = __shfl(idx, be + 2 + half);
      const int s2 = __shfl(idx, be + 4 + half);
      const int s3 = __shfl(idx, be + 6 + half);
      const uint4 q0 = *reinterpret_cast<const uint4*>(xbf + (size_t)s0 * DFEAT + l5 * 8);
      const uint4 q1 = *reinterpret_cast<const uint4*>(xbf + (size_t)s1 * DFEAT + l5 * 8);
      const uint4 q2 = *reinterpret_cast<const uint4*>(xbf + (size_t)s2 * DFEAT + l5 * 8);
      const uint4 q3 = *reinterpret_cast<const uint4*>(xbf + (size_t)s3 * DFEAT + l5 * 8);
      acc8(a, q0); acc8(a, q1); acc8(a, q2); acc8(a, q3);
      if (DOF) fm += mask[s0] + mask[s1] + mask[s2] + mask[s3];
    }
    // tail: uniform loop bound; shfl with clamped (active) source; work predicated.
    for (int e0 = be; e0 < m; e0 += 2) {
      const int e = e0 + half;
      const int s = __shfl(idx, (e < m) ? e : 0);
      if (e < m) {
        const uint4 q = *reinterpret_cast<const uint4*>(xbf + (size_t)s * DFEAT + l5 * 8);
        acc8(a, q);
        if (DOF) fm += mask[s];
      }
    }
  }
#pragma unroll
  for (int j = 0; j < 8; ++j) a[j] += __shfl_xor(a[j], 32);
  const float w = invd[wid];
  if (lane < 32) {
    uint4 r;
    r.x = (unsigned)f2bf(a[0] * w) | ((unsigned)f2bf(a[1] * w) << 16);
    r.y = (unsigned)f2bf(a[2] * w) | ((unsigned)f2bf(a[3] * w) << 16);
    r.z = (unsigned)f2bf(a[4] * w) | ((unsigned)f2bf(a[5] * w) << 16);
    r.w = (unsigned)f2bf(a[6] * w) | ((unsigned)f2bf(a[7] * w) << 16);
    *reinterpret_cast<uint4*>(outbf + (size_t)wid * DFEAT + l5 * 8) = r;
  }
  if (DOF) {
    fm += __shfl_xor(fm, 32);
    if (lane == 0) f[wid] = fm * w;
  }
}

// ---------------- final GEMM via MFMA bf16: barrier-free, B in regs, 32 rows/wave ----
// Each wave independently owns 32 rows (two 16-row tiles) x 256 cols. Per K-slice t:
// load ALL 16 B-fragments into regs (16 KB in flight, shared by both row tiles) +
// prefetch both next A-frags, then 32 MFMAs. No LDS, no barriers; B L2-traffic is
// halved vs 16-rows/wave and each load feeds 2 MFMAs.
__global__ __launch_bounds__(256, 2) void k_final_mfma(
    const unsigned short* __restrict__ m0bf, const unsigned short* __restrict__ mm0bf,
    const unsigned short* __restrict__ Bpk,
    const float* __restrict__ mask, const float* __restrict__ fbuf,
    const float* __restrict__ c1s, const float* __restrict__ c2s,
    const float* __restrict__ bcat, float* __restrict__ out, int N) {
  const int tid = threadIdx.x;
  const int lane = tid & 63;
  const int wave = tid >> 6;
  const int r0 = blockIdx.x * 128 + wave * 32;
  if (r0 >= N) return;  // wave-uniform; no barriers in kernel
  const int lr = lane & 15;  // A-row / D-col within tile
  const int lg = lane >> 4;  // k-group
  const uint4* Bv = reinterpret_cast<const uint4*>(Bpk);

  f32x4 acc[2][16];
#pragma unroll
  for (int fr = 0; fr < 2; ++fr)
#pragma unroll
    for (int c = 0; c < 16; ++c) acc[fr][c] = (f32x4){0.f, 0.f, 0.f, 0.f};

  const int arow0 = r0 + lr;
  const int arow1 = r0 + 16 + lr;
  const bool ok0 = arow0 < N, ok1 = arow1 < N;
  const size_t ab0 = (size_t)arow0 * DFEAT + lg * 8;
  const size_t ab1 = (size_t)arow1 * DFEAT + lg * 8;
  const bf16x8 zf = (bf16x8){0, 0, 0, 0, 0, 0, 0, 0};

  bf16x8 an0 = ok0 ? *reinterpret_cast<const bf16x8*>(m0bf + ab0) : zf;  // t=0
  bf16x8 an1 = ok1 ? *reinterpret_cast<const bf16x8*>(m0bf + ab1) : zf;

  for (int t = 0; t < 16; ++t) {
    // issue all 16 B-fragment loads (coalesced 1KB/wave each, independent)
    bf16x8 b[16];
#pragma unroll
    for (int c = 0; c < 16; ++c)
      b[c] = *reinterpret_cast<const bf16x8*>(&Bv[t * 1024 + c * 64 + lane]);
    const bf16x8 a0 = an0, a1 = an1;
    if (t < 15) {  // prefetch next A-fragments
      const unsigned short* As = (t + 1 < 8) ? m0bf : mm0bf;
      const int kb = ((t + 1) & 7) * 32;
      an0 = ok0 ? *reinterpret_cast<const bf16x8*>(As + ab0 + kb) : zf;
      an1 = ok1 ? *reinterpret_cast<const bf16x8*>(As + ab1 + kb) : zf;
    }
#pragma unroll
    for (int c = 0; c < 16; ++c) {
      acc[0][c] = __builtin_amdgcn_mfma_f32_16x16x32_bf16(a0, b[c], acc[0][c], 0, 0, 0);
      acc[1][c] = __builtin_amdgcn_mfma_f32_16x16x32_bf16(a1, b[c], acc[1][c], 0, 0, 0);
    }
  }

  // epilogue: tile fr rows rbase..rbase+3 (D row = lg*4+i), col = c*16+lr
#pragma unroll
  for (int fr = 0; fr < 2; ++fr) {
    const int rbase = r0 + fr * 16 + lg * 4;
    float mk[4], fv[4];
#pragma unroll
    for (int i = 0; i < 4; ++i) {
      int r = rbase + i;
      mk[i] = (r < N) ? mask[r] : 0.f;
      fv[i] = (r < N) ? fbuf[r] : 0.f;
    }
#pragma unroll
    for (int c = 0; c < 16; ++c) {
      const int col = c * 16 + lr;
      const float c1 = c1s[col], c2 = c2s[col], bc = bcat[col];
#pragma unroll
      for (int i = 0; i < 4; ++i) {
        const int r = rbase + i;
        if (r < N) out[(size_t)r * DFEAT + col] = acc[fr][c][i] + mk[i] * c1 + fv[i] * c2 + bc;
      }
    }
  }
}

// ---------------- host ----------------
extern "C" void kernel_launch(void* const* d_in, const int* in_sizes, int n_in,
                              void* d_out, int out_size, void* d_ws, size_t ws_size,
                              hipStream_t stream) {
  const float* x    = (const float*)d_in[0];
  const float* Wh_w = (const float*)d_in[1];
  const float* Wh_b = (const float*)d_in[2];
  const float* Wp_w = (const float*)d_in[3];
  const float* Wp_b = (const float*)d_in[4];
  const float* gate = (const float*)d_in[5];
  const float* hopw = (const float*)d_in[6];
  const int* src    = (const int*)d_in[7];
  const int* dst    = (const int*)d_in[8];

  const int H = in_sizes[5];
  const int E = in_sizes[7];
  const int N = in_sizes[0] / DFEAT;
  float* out = (float*)d_out;

  char* w = (char*)d_ws;
  auto take = [&](size_t bytes) -> char* {
    char* p = w;
    w += (bytes + 255) & ~(size_t)255;
    return p;
  };
  unsigned short* xbf   = (unsigned short*)take((size_t)N * DFEAT * 2);
  unsigned short* m0bf  = (unsigned short*)take((size_t)N * DFEAT * 2);
  unsigned short* mm0bf = (unsigned short*)take((size_t)N * DFEAT * 2);
  unsigned short* Bpk   = (unsigned short*)take((size_t)512 * 256 * 2);
  int* csr     = (int*)take((size_t)E * 4);
  int* offs    = (int*)take((size_t)(N + 1) * 4);
  int* cursor  = (int*)take((size_t)N * 4);
  int* deg     = (int*)take((size_t)N * 4);
  float* invd  = (float*)take((size_t)N * 4);
  float* mask  = (float*)take((size_t)N * 4);
  float* fbuf  = (float*)take((size_t)N * 4);
  float* Wbar  = (float*)take(65536 * 4);
  float* Wcat  = (float*)take(65536 * 4);
  float* W1    = (float*)take(65536 * 4);
  float* W2    = (float*)take(65536 * 4);
  float* bbar  = (float*)take(256 * 4);
  float* bcat  = (float*)take(256 * 4);
  float* c1s   = (float*)take(256 * 4);
  float* c2s   = (float*)take(256 * 4);
  float* sm    = (float*)take(64 * 4);
  int* bsum    = (int*)take(256 * 4);

  const int nScanBlocks = (N + 255) / 256;

  // graph structure
  hipMemsetAsync(deg, 0, (size_t)N * 4, stream);
  k_deg<<<(E + 255) / 256, 256, 0, stream>>>(dst, E, deg);
  k_scan1<<<nScanBlocks, 256, 0, stream>>>(deg, N, bsum);
  k_scan2<<<1, 256, 0, stream>>>(bsum, nScanBlocks);
  k_scan3<<<nScanBlocks, 256, 0, stream>>>(deg, bsum, N, offs, cursor, invd, mask);
  k_fill<<<(E + 255) / 256, 256, 0, stream>>>(src, dst, E, cursor, csr);

  // x -> bf16
  k_xbf<<<(N * DFEAT / 4 + 255) / 256, 256, 0, stream>>>(x, xbf, N * DFEAT / 4);

  // folded weights
  k_softmax<<<1, 64, 0, stream>>>(gate, H, hopw, sm);
  k_wbar<<<256, 256, 0, stream>>>(Wh_w, Wh_b, H, Wbar, bbar);
  k_wcat<<<256, 256, 0, stream>>>(Wp_w, Wp_b, sm, Wcat, bcat);
  k_mm<<<256, 256, 0, stream>>>(Wcat, Wbar, W1);
  k_mm<<<256, 256, 0, stream>>>(W1, Wbar, W2);
  k_cvec<<<1, 256, 0, stream>>>(Wcat, W1, bbar, sm, c1s, c2s);
  k_bprep<<<64, 256, 0, stream>>>(W1, W2, sm, Bpk);

  // m0bf = meanagg(xbf) ; mm0bf = meanagg(m0bf) (+ f = meanagg(mask))
  const int aggBlocks = (N + 3) / 4;
  k_aggb3<false><<<aggBlocks, 256, 0, stream>>>(xbf, csr, offs, invd, N, m0bf, nullptr, nullptr);
  k_aggb3<true><<<aggBlocks, 256, 0, stream>>>(m0bf, csr, offs, invd, N, mm0bf, mask, fbuf);

  // out = [m0|mm0] @ Bpk + mask*c1s + f*c2s + bcat
  k_final_mfma<<<(N + 127) / 128, 256, 0, stream>>>(m0bf, mm0bf, Bpk, mask, fbuf,
                                                    c1s, c2s, bcat, out, N);
}